// Round 10
// baseline (1331.007 us; speedup 1.0000x reference)
//
#include <hip/hip_runtime.h>
#include <math.h>

// ---- problem constants ----
#define BB    64
#define NN_   128
#define NH    6
#define DM    600     // d_model
#define RHID  300     // rnn hidden
#define DKH   100     // per-head dim
#define INDIM 360
#define G4    1200    // 4*RHID
#define WXROW 1206    // NH + 2*DM
#define DMP   608     // DM padded to mult of 32
#define INP   384     // INDIM padded
#define QKL   1536    // 2 * NH * 128 (head-padded q||k row length)
#define XGW   2400    // merged xg row width (fwd 0:1200, bwd 1200:2400)

// ---- LSTM cluster config (R9: fatter clusters, 15/dir instead of 25/dir) ----
#define S_CL  15      // clusters per direction
#define NSU   20      // units per cluster
#define NSR   80      // gate rows per cluster (4*NSU), 5 MFMA tiles of 16
#define NTL   5       // row tiles per cluster (NSR/16)
#define KPAD  320
#define HSLOT (BB*KPAD)          // 20480 bf16 per history slot
#define DSTR  (129*HSLOT)        // per-dir history stride (bf16)

// R8 measured: AGENT == SYSTEM on gfx950 (per-XCD L2 non-coherent -> agent
// coherence point is also MALL). Keep AGENT; the lever is now structure.
#define COMM_SCOPE __HIP_MEMORY_SCOPE_AGENT

// ---- workspace layout (float offsets). Peak ~ 26.35M fl = 105.4 MB ----
#define OFF_GINB   0ull                 // bf16 [8192][608] = 2,490,368 fl
#define OFF_ASPECT 2490368ull
#define OFF_ASCB   2573568ull
#define OFF_W1SUM  2622720ull
#define OFF_W2SUM  2623360ull
#define OFF_SWX    2624000ull
#define OFF_SBX    2624016ull
#define OFF_SGI    2624032ull           // fp32 [8192][2] interleaved (sg1,sg2)
#define OFF_WHS    2640416ull           // fp32 [64][128][128]
#define OFF_WQKP   3688992ull           // bf16 [1536][608] = 466,944 fl
#define OFF_BQK    4155936ull           // fp32 1536
#define OFF_WWP    4157472ull           // bf16 [600][608] = 182,400 fl
#define OFF_WXXP   4339872ull           // bf16 [300][608] = 91,200 fl
#define OFF_WIHP   4431072ull           // bf16 [2400][384] = 460,800 fl
#define OFF_BP     4891872ull           // fp32 [2400]
#define OFF_WTB    4894272ull           // bf16 [2][1200][320] = 384,000 fl
#define OFF_EMBS   5278272ull           // bf16 [8192][384] = 1,572,864 fl
#define ARENA      6851136ull
#define OFF_XG     (ARENA)                      // bf16 [8192][2400] = 9,830,400 fl
#define OFF_HIST   (ARENA + 9830400ull)         // bf16 [2][129][64][320] = 2,641,920 fl
#define OFF_FLAGS  (ARENA + 12472320ull)        // flags (30, 128B apart)
// post-lstm reuse (xg dead after lstm; hist/flags dead after lstm):
#define OFF_QKH    (ARENA)                      // bf16 [8192][1536] = 6,291,456 fl (over xg)
#define OFF_ADJ    (ARENA + 6291456ull)         // bf16 [64][6][128][128] = 3,145,728 fl
#define OFF_ADJS   (ARENA + 16121856ull)        // bf16 [64][128][128] = 524,288 fl
#define OFF_GINT   (ARENA + 16646144ull)        // bf16 [64][608][128] = 2,490,368 fl
#define OFF_W12    (ARENA + 19136512ull)        // bf16 [2][608] = 608 fl
#define OFF_WDM    (ARENA + 19137152ull)        // fp32 [6][600][100] = 360,000 fl
#define OFF_BDM    (ARENA + 19497152ull)        // fp32 600
#define OFF_AXB    (ARENA)                      // bf16 (over qkh, dead after attn2/ascf)
#define OFF_G1B    (ARENA + 2490368ull)
#define OFF_G1T    (OFF_GINT)
#define OFF_AX2B   (ARENA + 4980736ull)
#define OFF_G2B    (ARENA + 7471104ull)         // over adj (dead after adjsum)
#define OFF_HNB    (ARENA + 9961472ull)         // bf16 [8192][300] (over hist, dead)

// ---- pack_k segmented index space ----
#define PK0 (XGW*INP + XGW)                 //   924,000 wihp + bias
#define PK1 (PK0 + QKL*DMP + QKL)           // 1,859,424 wqkhp + bias
#define PK2 (PK1 + DM*DMP)                  // 2,224,224 Ww pack
#define PK3 (PK2 + RHID*DMP)                // 2,406,624 Wxx pack
#define PK4 (PK3 + 2*G4*KPAD)               // 3,174,624 Whh both dirs
#define PK5 (PK4 + 22528)                   // 3,197,152 hist slot0 + flags init
#define PK6 (PK5 + 32768)                   // 3,229,920 ginb pad cols [600,608) = 0

typedef __bf16 bf16x8 __attribute__((ext_vector_type(8)));
typedef __bf16 bf16x4 __attribute__((ext_vector_type(4)));
typedef __bf16 bf16x2 __attribute__((ext_vector_type(2)));
typedef float  f32x4  __attribute__((ext_vector_type(4)));

__device__ __forceinline__ float sigm(float x){ return 1.f/(1.f+__expf(-x)); }
__device__ __forceinline__ float selu_f(float x){
  const float sc=1.0507009873554805f, al=1.6732632423543772f;
  return x>0.f ? sc*x : sc*al*(__expf(x)-1.f);
}
__device__ __forceinline__ bf16x8 bzero8(){
  bf16x8 z;
#pragma unroll
  for (int j=0;j<8;++j) z[j]=(__bf16)0.f;
  return z;
}

// ---------------- embedding concat -> bf16 [8192][384], pads written zero ----------------
__global__ __launch_bounds__(384) void embed_k(
    const int* __restrict__ tok, const int* __restrict__ pos_ids, const int* __restrict__ post_ids,
    const float* __restrict__ emb_w, const float* __restrict__ pos_w, const float* __restrict__ post_w,
    __bf16* __restrict__ embs)
{
  int bn = blockIdx.x, t = threadIdx.x;
  float v = 0.f;
  if      (t < 300) v = emb_w [(size_t)tok     [bn]*300 + t];
  else if (t < 330) v = pos_w [(size_t)pos_ids [bn]*30  + (t-300)];
  else if (t < 360) v = post_w[(size_t)post_ids[bn]*30  + (t-330)];
  embs[(size_t)bn*INP + t] = (__bf16)v;
}

// ---------------- Wx folded constants (+ bf16 w12 for the sg GEMV) ----------------
__global__ __launch_bounds__(640) void consts_k(
    const float* __restrict__ Wx, const float* __restrict__ bx,
    float* __restrict__ w1sum, float* __restrict__ w2sum,
    float* __restrict__ swx, float* __restrict__ sbx, __bf16* __restrict__ w12)
{
  int t = threadIdx.x;
  if (t < DM){
    float s1=0.f, s2=0.f;
    for (int k=0;k<NH;++k){ s1 += Wx[k*WXROW + NH + t]; s2 += Wx[k*WXROW + NH + DM + t]; }
    w1sum[t]=s1; w2sum[t]=s2;
    w12[t]=(__bf16)s1; w12[DMP+t]=(__bf16)s2;
  } else if (t < DM+NH){
    int h=t-DM; float s=0.f;
    for (int k=0;k<NH;++k) s += Wx[k*WXROW + h];
    swx[h]=s;
  } else if (t == DM+NH){
    float s=0.f; for (int k=0;k<NH;++k) s += bx[k];
    sbx[0]=s;
  }
  if (t >= DM && t < DMP){ w12[t]=(__bf16)0.f; w12[DMP+t]=(__bf16)0.f; }
}

// ---------------- WdM[h][D][e] = sum_d Wd[d][D]*wm[h][d][e]; bdM[h][e] = bd·wm[h][:,e] ----------------
__global__ __launch_bounds__(128) void wdm_k(
    const float* __restrict__ Wd, const float* __restrict__ bd, const float* __restrict__ wm,
    float* __restrict__ WdM, float* __restrict__ bdM)
{
  int D = blockIdx.x, h = blockIdx.y, e = threadIdx.x;
  if (e >= DKH) return;
  float s = 0.f;
  for (int d=0; d<DKH; ++d)
    s += Wd[d*DM + D] * wm[(h*DKH+d)*DKH + e];
  WdM[((size_t)h*DM + D)*DKH + e] = s;
  if (D == 0){
    float sb = 0.f;
    for (int d=0; d<DKH; ++d) sb += bd[d]*wm[(h*DKH+d)*DKH + e];
    bdM[h*DKH + e] = sb;
  }
}

// ---------------- fused packing/init (segmented): wihp|wqkhp|Ww|Wxx|Whh|init|ginb-pads ----------------
__global__ __launch_bounds__(256) void pack_k(
    const float* __restrict__ Wih_f, const float* __restrict__ b_f,
    const float* __restrict__ Wih_b, const float* __restrict__ b_b,
    const float* __restrict__ Wq, const float* __restrict__ bq,
    const float* __restrict__ Wk, const float* __restrict__ bk,
    const float* __restrict__ Ww, const float* __restrict__ Wxx,
    const float* __restrict__ Whh_f, const float* __restrict__ Whh_b,
    __bf16* __restrict__ wihp, float* __restrict__ bp,
    __bf16* __restrict__ wqkp, float* __restrict__ bqk,
    __bf16* __restrict__ wwp, __bf16* __restrict__ wxxp,
    __bf16* __restrict__ wtb, float* __restrict__ ws)
{
  int idx = blockIdx.x*256 + threadIdx.x;
  if (idx < PK0){
    if (idx < XGW*INP){
      int r = idx / INP, k = idx - r*INP;
      int dir = r >= G4; int p = r - dir*G4;
      const float* W = dir ? Wih_b : Wih_f;
      int srow = (p&3)*RHID + (p>>2);
      wihp[idx] = (k<INDIM) ? (__bf16)W[(size_t)srow*INDIM + k] : (__bf16)0.f;
    } else {
      int n = idx - XGW*INP;
      int dir = n >= G4; int p = n - dir*G4;
      const float* b = dir ? b_b : b_f;
      bp[n] = b[(p&3)*RHID + (p>>2)];
    }
  } else if (idx < PK1){
    int id = idx - PK0;
    if (id < QKL*DMP){
      int n = id / DMP, k = id - n*DMP;
      int nl = (n < 768) ? n : n - 768;
      int h = nl >> 7, e = nl & 127;
      float v = 0.f;
      if (k < DM && e < DKH)
        v = (n < 768) ? Wq[(size_t)(h*DKH+e)*DM + k] : Wk[(size_t)(h*DKH+e)*DM + k];
      wqkp[id] = (__bf16)v;
    } else {
      int n = id - QKL*DMP;
      int nl = (n < 768) ? n : n - 768;
      int h = nl >> 7, e = nl & 127;
      bqk[n] = (e < DKH) ? ((n < 768) ? bq[h*DKH+e] : bk[h*DKH+e]) : 0.f;
    }
  } else if (idx < PK2){
    int id = idx - PK1;
    int n = id / DMP, k = id - n*DMP;
    wwp[id] = (k < DM) ? (__bf16)Ww[(size_t)n*DM + k] : (__bf16)0.f;
  } else if (idx < PK3){
    int id = idx - PK2;
    int n = id / DMP, k = id - n*DMP;
    wxxp[id] = (k < DM) ? (__bf16)Wxx[(size_t)n*DM + k] : (__bf16)0.f;
  } else if (idx < PK4){
    int id = idx - PK3;
    int dir = id >= G4*KPAD; int id2 = id - dir*G4*KPAD;
    int p = id2 / KPAD, k = id2 - p*KPAD;
    const float* Whh = dir ? Whh_b : Whh_f;
    wtb[id] = (k < RHID) ? (__bf16)Whh[((size_t)((p&3)*RHID + (p>>2)))*RHID + k] : (__bf16)0.f;
  } else if (idx < PK5){
    int id = idx - PK4;
    if (id < 10240)      ws[OFF_HIST + id] = 0.f;                        // dir0 slot0
    else if (id < 20480) ws[OFF_HIST + 1320960ull + (id-10240)] = 0.f;   // dir1 slot0
    else                 ws[OFF_FLAGS + (id-20480)] = 0.f;               // flags
  } else if (idx < PK6){
    // ginb pad cols [600,608) = 0 (lstm epilogue writes only [0,600))
    int id = idx - PK5;
    ((unsigned*)ws)[(size_t)(id>>2)*(DMP/2) + (DM/2) + (id&3)] = 0u;
  }
}

// ---------------- LDS-free bf16 MFMA GEMM: C = act(A @ B^T + bias) ----------------
// Dual accumulator chains (even/odd kt) double per-wave MFMA ILP.
template<int KT, int ACT, int OBF>
__global__ __launch_bounds__(256) void wgemm_k(
    const __bf16* __restrict__ A, const __bf16* __restrict__ B,
    const float* __restrict__ bias, void* __restrict__ Cout,
    int Nn, int Npad, int ldc,
    long long sA, long long sB, long long sC)
{
  const int tid = threadIdx.x, lane = tid & 63, wave = tid >> 6;
  const int fn = lane & 15, fq = lane >> 4;
  const int K = KT*32;
  const __bf16* Ab = A + (size_t)blockIdx.z * (size_t)sA;
  const __bf16* Bb = B + (size_t)blockIdx.z * (size_t)sB;
  float*  Cf = (float*) Cout + (size_t)blockIdx.z * (size_t)sC;
  __bf16* Ch = (__bf16*)Cout + (size_t)blockIdx.z * (size_t)sC;

  const int m0 = (blockIdx.x*4 + wave)*16;

  bf16x8 Af[KT];
#pragma unroll
  for (int kt=0; kt<KT; ++kt)
    Af[kt] = *(const bf16x8*)(Ab + (size_t)(m0 + fn)*K + kt*32 + fq*8);

  for (int n0 = blockIdx.y*16; n0 < Nn; n0 += 16*gridDim.y){
    const int gn = n0 + fn;
    const int gnc = (gn < Nn) ? gn : 0;
    f32x4 acc0 = {0.f,0.f,0.f,0.f};
    f32x4 acc1 = {0.f,0.f,0.f,0.f};
#pragma unroll
    for (int kt=0; kt<KT; ++kt){
      bf16x8 Bf = *(const bf16x8*)(Bb + (size_t)gnc*K + kt*32 + fq*8);
      if (gn >= Nn) Bf = bzero8();
      if (kt & 1) acc1 = __builtin_amdgcn_mfma_f32_16x16x32_bf16(Af[kt], Bf, acc1, 0, 0, 0);
      else        acc0 = __builtin_amdgcn_mfma_f32_16x16x32_bf16(Af[kt], Bf, acc0, 0, 0, 0);
    }
    float bv = (bias && gn < Nn) ? bias[gn] : 0.f;
#pragma unroll
    for (int r=0; r<4; ++r){
      int gm = m0 + fq*4 + r;
      float v = acc0[r] + acc1[r] + bv;
      if (ACT==1) v = selu_f(v);
      else if (ACT==2) v = fmaxf(v, 0.f);
      if (gn < Nn){
        if (OBF) Ch[(size_t)gm*ldc + gn] = (__bf16)v;
        else     Cf[(size_t)gm*ldc + gn] = v;
      } else if (gn < Npad){
        if (OBF) Ch[(size_t)gm*ldc + gn] = (__bf16)0.f;
        else     Cf[(size_t)gm*ldc + gn] = 0.f;
      }
    }
  }
}

// ---------------- bf16 per-batch transpose [64][128][608] -> [64][608][128] ----------------
__global__ __launch_bounds__(256) void tr_k(
    const __bf16* __restrict__ in, __bf16* __restrict__ out)
{
  const int b = blockIdx.z, m0 = blockIdx.y*64, d0 = blockIdx.x*64;
  const int tid = threadIdx.x;
  __shared__ __align__(16) __bf16 T[64][72];
  const __bf16* ib = in + (size_t)b*NN_*DMP;
  __bf16* ob = out + (size_t)b*DMP*NN_;
#pragma unroll
  for (int r=0;r<2;++r){
    int idx = tid + 256*r;
    int mi = idx>>3, ch = idx&7;
    int d = d0 + ch*8;
    bf16x8 v = bzero8();
    if (d < DMP) v = *(const bf16x8*)(ib + (size_t)(m0+mi)*DMP + d);
    *(bf16x8*)&T[mi][ch*8] = v;
  }
  __syncthreads();
#pragma unroll
  for (int r=0;r<2;++r){
    int idx = tid + 256*r;
    int di = idx>>3, mch = idx&7;
    int d = d0 + di;
    if (d >= DMP) continue;
    bf16x8 v;
#pragma unroll
    for (int j=0;j<8;++j) v[j] = T[mch*8+j][di];
    *(bf16x8*)(ob + (size_t)d*NN_ + m0 + mch*8) = v;
  }
}

// ---------------- cooperative-cluster MFMA LSTM — R9: 15 fat clusters/dir ----
// R8 established AGENT==SYSTEM (MALL floor ~1.2k cy/leg). This round attacks
// the NON-leg costs: detection tail (max over cluster set) and MALL contention
// from spinner waves. 15 clusters/dir (NSR=80 rows, 5 MFMA tiles) instead of
// 25 (48 rows, 3 tiles): 30 blocks total, 30 poller waves (was 100 across 2
// poller waves/block — dual-poller dropped), poll set 15 (was 25), and 1.67x
// compute per block to hide leg latency. Protocol otherwise identical
// (fence-free relaxed AGENT atomics; data drained via __syncthreads before
// flag release; gates in-register via operand-swapped MFMA, acc[nt][0..3] =
// i,f,g,o of unit u = sl*20 + nt*4 + fq for batch b = wave*16+fn).
__global__ __launch_bounds__(256, 1) void lstm_mfma_k(
    const __bf16* __restrict__ xg,
    const __bf16* __restrict__ wtb,
    __bf16* hist, int* flags,
    __bf16* __restrict__ ginb,
    const float* __restrict__ mask, float* __restrict__ aspect)
{
  const int blk = blockIdx.x;
  const int dir = blk / S_CL, sl = blk - dir*S_CL;
  const int tid = threadIdx.x, lane = tid & 63, wave = tid >> 6;
  const int p0 = sl * NSR;
  const __bf16* W = wtb + (size_t)dir * G4 * KPAD;
  __bf16* hb = hist + (size_t)dir * DSTR;

  const int fn = lane & 15, fq = lane >> 4, fk = fq*8;
  const int b  = wave*16 + fn;

  __shared__ volatile int done_s;
  __shared__ float mskL[NN_*BB];        // [n][b] transposed, 32 KB
  if (tid == 0) done_s = 0;
  for (int i = tid; i < BB*NN_; i += 256){
    int bb = i >> 7, nn = i & 127;
    mskL[nn*BB + bb] = mask[i];
  }

  bf16x8 Wf[NTL][10];
#pragma unroll
  for (int nt = 0; nt < NTL; ++nt)
#pragma unroll
    for (int kt = 0; kt < 10; ++kt)
      Wf[nt][kt] = *(const bf16x8*)(W + (size_t)(p0 + nt*16 + fn)*KPAD + kt*32 + fk);

  float cst[NTL] = {0.f,0.f,0.f,0.f,0.f};
  float asp[NTL] = {0.f,0.f,0.f,0.f,0.f};
  float wnacc  = 0.f;
  const __bf16* xb = xg + (size_t)b*NN_*XGW + dir*G4 + p0 + fq*4;
  const int u0 = sl*NSU + fq;                 // + nt*4 -> unit in [0,300)
  __syncthreads();

  for (int s = 0; s < NN_; ++s){
    const int n_t = dir ? (NN_-1-s) : s;
    const __bf16* hbr = hb + (size_t)s*HSLOT + (size_t)b*KPAD;
    __bf16*       hbw = hb + (size_t)(s+1)*HSLOT + (size_t)b*KPAD;

    unsigned long long xv[NTL];
#pragma unroll
    for (int nt = 0; nt < NTL; ++nt)
      xv[nt] = *(const unsigned long long*)(xb + (size_t)n_t*XGW + nt*16);
    const float mval = mskL[n_t*BB + b];

    bf16x8 Hf[10];
#pragma unroll
    for (int kt = 0; kt < 10; ++kt){
      const unsigned long long* hp = (const unsigned long long*)(hbr + kt*32 + fk);
      union { unsigned long long u[2]; bf16x8 v; } cv;
      cv.u[0] = __hip_atomic_load(hp,   __ATOMIC_RELAXED, COMM_SCOPE);
      cv.u[1] = __hip_atomic_load(hp+1, __ATOMIC_RELAXED, COMM_SCOPE);
      Hf[kt] = cv.v;
    }

    f32x4 acc[NTL];
#pragma unroll
    for (int nt = 0; nt < NTL; ++nt) acc[nt] = (f32x4){0.f,0.f,0.f,0.f};
#pragma unroll
    for (int kt = 0; kt < 10; ++kt)
#pragma unroll
      for (int nt = 0; nt < NTL; ++nt)
        acc[nt] = __builtin_amdgcn_mfma_f32_16x16x32_bf16(Wf[nt][kt], Hf[kt], acc[nt], 0, 0, 0);

    __bf16 hsv[NTL];
#pragma unroll
    for (int nt = 0; nt < NTL; ++nt){
      union { unsigned long long u; __bf16 g[4]; } xu; xu.u = xv[nt];
      float ig = sigm (acc[nt][0] + (float)xu.g[0]);
      float fg = sigm (acc[nt][1] + (float)xu.g[1]);
      float gg = tanhf(acc[nt][2] + (float)xu.g[2]);
      float og = sigm (acc[nt][3] + (float)xu.g[3]);
      float c = fg*cst[nt] + ig*gg; cst[nt] = c;
      float hval = og * tanhf(c);
      asp[nt] += hval * mval;
      union { unsigned short us; __bf16 h; } pk; pk.h = (__bf16)hval;
      hsv[nt] = pk.h;
      // hist store MUST precede the flag -> stays in the pre-barrier drain.
      __hip_atomic_store((unsigned short*)(hbw + u0 + nt*4), pk.us,
                         __ATOMIC_RELAXED, COMM_SCOPE);
    }
    wnacc += mval;

    __syncthreads();   // drains hist stores (vmcnt0) before flag release
    if (tid == 0)
      __hip_atomic_store(&flags[(dir*S_CL + sl)*32], s+1,
                         __ATOMIC_RELAXED, COMM_SCOPE);
    // Deferred ginb stores: issued after flag; their drain overlaps poll/next-step
    // latency (they complete by the next iteration's __syncthreads).
#pragma unroll
    for (int nt = 0; nt < NTL; ++nt)
      ginb[(size_t)(b*NN_ + n_t)*DMP + dir*RHID + u0 + nt*4] = hsv[nt];
    // Single poller wave (R9): fewer MALL spinners; poll loop self-paces at
    // the uncached-load latency, no sleep needed.
    if (wave == 0){
      int* fp = &flags[(dir*S_CL + (lane < S_CL ? lane : 0))*32];
      bool ok = (lane >= S_CL);
      while (done_s < s+1){
        if (!ok) ok = (__hip_atomic_load(fp, __ATOMIC_RELAXED, COMM_SCOPE) >= s+1);
        if (__all((int)ok)){ done_s = s+1; break; }
      }
    }
    __syncthreads();
  }

  const float invwn = 1.f / wnacc;
#pragma unroll
  for (int nt = 0; nt < NTL; ++nt)
    aspect[b*DM + dir*RHID + u0 + nt*4] = asp[nt]*invwn;
}

// ---------------- fused: aw = aspect@WdM + bdM ; asc = tanh(aw·k + bias_m) ----------------
__global__ __launch_bounds__(128) void ascf_k(
    const float* __restrict__ aspect, const float* __restrict__ WdM, const float* __restrict__ bdM,
    const __bf16* __restrict__ qkh, const float* __restrict__ bias_m, float* __restrict__ asc)
{
  int b = blockIdx.x, h = blockIdx.y, t = threadIdx.x;
  __shared__ __align__(16) float asp[DM];
  __shared__ __align__(16) float awl[DKH];
  for (int i = t; i < DM; i += 128) asp[i] = aspect[b*DM + i];
  __syncthreads();
  if (t < DKH){
    const float* wrow = WdM + (size_t)h*DM*DKH + t;
    float s0=0.f,s1=0.f,s2=0.f,s3=0.f;
    for (int D=0; D<DM; D+=4){
      s0 += asp[D+0]*wrow[(size_t)(D+0)*DKH];
      s1 += asp[D+1]*wrow[(size_t)(D+1)*DKH];
      s2 += asp[D+2]*wrow[(size_t)(D+2)*DKH];
      s3 += asp[D+3]*wrow[(size_t)(D+3)*DKH];
    }
    awl[t] = s0+s1+s2+s3 + bdM[h*DKH + t];
  }
  __syncthreads();
  const __bf16* kr = qkh + (size_t)(b*NN_ + t)*QKL + 768 + h*128;
  float s=0.f;
#pragma unroll
  for (int e=0;e<DKH;e+=2){
    bf16x2 kv = *(const bf16x2*)(kr + e);
    s += awl[e]*(float)kv[0] + awl[e+1]*(float)kv[1];
  }
  asc[(b*NH+h)*NN_ + t] = tanhf(s + bias_m[0]);
}

// ---------------- MFMA attention (split x2): scores + mask + short + softmax -> adj bf16 ----------------
__global__ __launch_bounds__(256) void attn2_k(
    const __bf16* __restrict__ qkh, const float* __restrict__ asc,
    const float* __restrict__ shortm, const int* __restrict__ tok,
    __bf16* __restrict__ adj)
{
  const int bx = blockIdx.x;
  const int bh = bx >> 1, half = bx & 1;
  const int b = bh / NH, h = bh - b*NH;
  const int tid = threadIdx.x, lane = tid & 63, wave = tid >> 6;
  const int fn = lane & 15, fq = lane >> 4;
  const __bf16* qb = qkh + (size_t)(b*NN_)*QKL + h*128;
  const __bf16* kb = qkh + (size_t)(b*NN_)*QKL + 768 + h*128;

  const int m0 = half*64 + wave*16;
  bf16x8 Af[4];
#pragma unroll
  for (int kt=0;kt<4;++kt)
    Af[kt] = *(const bf16x8*)(qb + (size_t)(m0+fn)*QKL + kt*32 + fq*8);

  f32x4 acc[8];
#pragma unroll
  for (int j=0;j<8;++j) acc[j] = (f32x4){0.f,0.f,0.f,0.f};

#pragma unroll
  for (int j=0;j<8;++j){
    bf16x8 Bf[4];
#pragma unroll
    for (int kt=0;kt<4;++kt)
      Bf[kt] = *(const bf16x8*)(kb + (size_t)(j*16+fn)*QKL + kt*32 + fq*8);
#pragma unroll
    for (int kt=0;kt<4;++kt)
      acc[j] = __builtin_amdgcn_mfma_f32_16x16x32_bf16(Af[kt], Bf[kt], acc[j], 0,0,0);
  }

  float ascv[8]; int msk[8];
#pragma unroll
  for (int j=0;j<8;++j){
    int c = j*16 + fn;
    ascv[j] = asc[(b*NH+h)*NN_ + c];
    msk [j] = tok[b*NN_ + c];
  }

#pragma unroll
  for (int r=0;r<4;++r){
    int m = m0 + fq*4 + r;
    float sv[8];
#pragma unroll
    for (int j=0;j<8;++j){
      int c = j*16 + fn;
      float s = acc[j][r]*0.1f + ascv[j];
      if (msk[j]==0) s = -1e9f;
      s += shortm[((size_t)(b*NN_+m))*NN_ + c];
      sv[j]=s;
    }
    float mx = sv[0];
#pragma unroll
    for (int j=1;j<8;++j) mx = fmaxf(mx, sv[j]);
#pragma unroll
    for (int o=1;o<16;o<<=1) mx = fmaxf(mx, __shfl_xor(mx, o, 64));
    float sum = 0.f, ev[8];
#pragma unroll
    for (int j=0;j<8;++j){ ev[j]=__expf(sv[j]-mx); sum+=ev[j]; }
#pragma unroll
    for (int o=1;o<16;o<<=1) sum += __shfl_xor(sum, o, 64);
    float inv = 1.f/sum;
#pragma unroll
    for (int j=0;j<8;++j)
      adj[(((size_t)(b*NH+h))*NN_ + m)*NN_ + j*16 + fn] = (__bf16)(ev[j]*inv);
  }
}

// ---------------- adjsum (bf16 in) -> bf16 adjs (/H) + fp32 whs ----------------
__global__ __launch_bounds__(256) void adjsum_k(
    const __bf16* __restrict__ adj, const float* __restrict__ swx,
    __bf16* __restrict__ adjs, float* __restrict__ whs)
{
  int idx = blockIdx.x*256 + threadIdx.x;
  int b = idx >> 14, rem = idx & 16383;
  float s=0.f, w=0.f;
  for (int h=0;h<NH;++h){
    float v = (float)adj[(((size_t)b*NH+h)<<14) + rem];
    s += v; w += v*swx[h];
  }
  adjs[idx] = (__bf16)(s*(1.f/NH));
  whs [idx] = w*(1.f/NH);
}

// ---------------- adjs2[b,i,j] = whs + (sg1[b,j]+sg2[b,i]+sbx)/H -> bf16 ----------------
__global__ __launch_bounds__(256) void adjsum2_k(
    const float* __restrict__ whs, const float* __restrict__ sgi,
    const float* __restrict__ sbx, __bf16* __restrict__ adjs)
{
  int idx = blockIdx.x*256 + threadIdx.x;
  int b = idx >> 14, rem = idx & 16383;
  int i = rem >> 7, j = rem & 127;
  adjs[idx] = (__bf16)(whs[idx] + (sgi[(b*NN_+j)*2] + sgi[(b*NN_+i)*2+1] + sbx[0])*(1.f/NH));
}

// ---------------- pooled mean + logits (bf16 hn) ----------------
__global__ __launch_bounds__(320) void pooled_k(
    const __bf16* __restrict__ hn, const float* __restrict__ mask,
    const float* __restrict__ Wc, const float* __restrict__ bc, float* __restrict__ out)
{
  int b=blockIdx.x, t=threadIdx.x;
  __shared__ float msk[NN_];
  __shared__ float pl[RHID];
  __shared__ float wn;
  if (t<NN_) msk[t]=mask[b*NN_+t];
  __syncthreads();
  if (t==0){ float s=0.f; for (int n=0;n<NN_;++n) s+=msk[n]; wn=s; }
  __syncthreads();
  if (t<RHID){
    float s=0.f;
    for (int n=0;n<NN_;++n) s += (float)hn[((size_t)(b*NN_+n))*RHID+t]*msk[n];
    pl[t]=s/wn;
  }
  __syncthreads();
  if (t<3){
    float s=bc[t];
    for (int d=0;d<RHID;++d) s += pl[d]*Wc[t*RHID+d];
    out[b*3+t]=s;
  }
}

extern "C" void kernel_launch(void* const* d_in, const int* in_sizes, int n_in,
                              void* d_out, int out_size, void* d_ws, size_t ws_size,
                              hipStream_t stream)
{
  (void)in_sizes; (void)n_in; (void)out_size; (void)ws_size;
  const int*   tok      = (const int*)  d_in[0];
  const int*   pos_ids  = (const int*)  d_in[2];
  const int*   post_ids = (const int*)  d_in[5];
  const float* mask     = (const float*)d_in[6];
  const float* shortm   = (const float*)d_in[8];
  const float* emb_w    = (const float*)d_in[9];
  const float* pos_w    = (const float*)d_in[10];
  const float* post_w   = (const float*)d_in[11];
  const float* Wih_f    = (const float*)d_in[12];
  const float* Whh_f    = (const float*)d_in[13];
  const float* b_f      = (const float*)d_in[14];
  const float* Wih_b    = (const float*)d_in[15];
  const float* Whh_b    = (const float*)d_in[16];
  const float* b_b      = (const float*)d_in[17];
  const float* Wq       = (const float*)d_in[18];
  const float* bq       = (const float*)d_in[19];
  const float* Wk       = (const float*)d_in[20];
  const float* bk       = (const float*)d_in[21];
  const float* Wd       = (const float*)d_in[22];
  const float* bd       = (const float*)d_in[23];
  const float* weight_m = (const float*)d_in[24];
  const float* bias_m   = (const float*)d_in[25];
  const float* Ww       = (const float*)d_in[26];
  const float* bw       = (const float*)d_in[27];
  const float* Wx       = (const float*)d_in[28];
  const float* bx       = (const float*)d_in[29];
  const float* Wxx      = (const float*)d_in[30];
  const float* bxx      = (const float*)d_in[31];
  const float* Wc       = (const float*)d_in[32];
  const float* bc       = (const float*)d_in[33];

  float* ws  = (float*)d_ws;
  float* out = (float*)d_out;

  __bf16* ginb  = (__bf16*)(ws + OFF_GINB);
  float* aspect = ws + OFF_ASPECT;
  float* ascb   = ws + OFF_ASCB;
  float* w1sum  = ws + OFF_W1SUM;
  float* w2sum  = ws + OFF_W2SUM;
  float* swx    = ws + OFF_SWX;
  float* sbx    = ws + OFF_SBX;
  float* sgi    = ws + OFF_SGI;
  float* whs    = ws + OFF_WHS;
  __bf16* wqkp  = (__bf16*)(ws + OFF_WQKP);
  float* bqk    = ws + OFF_BQK;
  __bf16* wwp   = (__bf16*)(ws + OFF_WWP);
  __bf16* wxxp  = (__bf16*)(ws + OFF_WXXP);
  __bf16* wihp  = (__bf16*)(ws + OFF_WIHP);
  float* bp     = ws + OFF_BP;
  __bf16* wtb   = (__bf16*)(ws + OFF_WTB);
  __bf16* embs  = (__bf16*)(ws + OFF_EMBS);
  __bf16* xg    = (__bf16*)(ws + OFF_XG);
  __bf16* hist  = (__bf16*)(ws + OFF_HIST);
  int*   flags  = (int*)(ws + OFF_FLAGS);
  __bf16* qkh   = (__bf16*)(ws + OFF_QKH);
  __bf16* adjb  = (__bf16*)(ws + OFF_ADJ);
  __bf16* adjs  = (__bf16*)(ws + OFF_ADJS);
  __bf16* gint  = (__bf16*)(ws + OFF_GINT);
  __bf16* w12   = (__bf16*)(ws + OFF_W12);
  float* wdm    = ws + OFF_WDM;
  float* bdm    = ws + OFF_BDM;
  __bf16* axb   = (__bf16*)(ws + OFF_AXB);
  __bf16* g1b   = (__bf16*)(ws + OFF_G1B);
  __bf16* g1t   = (__bf16*)(ws + OFF_G1T);
  __bf16* ax2b  = (__bf16*)(ws + OFF_AX2B);
  __bf16* g2b   = (__bf16*)(ws + OFF_G2B);
  __bf16* hnb   = (__bf16*)(ws + OFF_HNB);

  // 1. embeddings, constants, fused packing/init (also zeroes ginb pad cols)
  embed_k<<<dim3(BB*NN_),384,0,stream>>>(tok,pos_ids,post_ids,emb_w,pos_w,post_w,embs);
  consts_k<<<1,640,0,stream>>>(Wx,bx,w1sum,w2sum,swx,sbx,w12);
  wdm_k<<<dim3(DM,NH),128,0,stream>>>(Wd,bd,weight_m,wdm,bdm);
  pack_k<<<dim3((PK6+255)/256),256,0,stream>>>(Wih_f,b_f,Wih_b,b_b,Wq,bq,Wk,bk,Ww,Wxx,
                                               Whh_f,Whh_b,wihp,bp,wqkp,bqk,wwp,wxxp,wtb,ws);
  // 2. merged LSTM input projection (both dirs), bf16 out [8192][2400]
  wgemm_k<12,0,1><<<dim3(128,8,1),256,0,stream>>>(embs,wihp,bp,xg, XGW,XGW,XGW, 0,0,0);
  // 3. recurrence — R9: 15 fat clusters/dir, single poller wave.
  lstm_mfma_k<<<dim3(2*S_CL),256,0,stream>>>(xg,wtb,hist,flags,ginb,mask,aspect);
  // 4. fused Q||K projection (bf16 head-padded), aspect-biased scores input
  wgemm_k<19,0,1><<<dim3(128,12,1),256,0,stream>>>(ginb,wqkp,bqk,qkh, QKL,QKL,QKL, 0,0,0);
  ascf_k<<<dim3(BB,NH),128,0,stream>>>(aspect,wdm,bdm,qkh,bias_m,ascb);
  // 5. MFMA scores + softmax -> adj bf16
  attn2_k<<<dim3(BB*NH*2),256,0,stream>>>(qkh,ascb,shortm,tok,adjb);
  // 6. GCN layer 1 (bf16 MFMA)
  adjsum_k<<<4096,256,0,stream>>>(adjb,swx,adjs,whs);
  tr_k<<<dim3(10,2,BB),256,0,stream>>>(ginb,gint);
  wgemm_k<4,0,1><<<dim3(2,4,BB),256,0,stream>>>(adjs,gint,nullptr,axb, DM,DMP,DMP, 16384,(long long)DMP*NN_,(long long)NN_*DMP);
  wgemm_k<19,1,1><<<dim3(128,8,1),256,0,stream>>>(axb,wwp,bw,g1b, DM,DMP,DMP, 0,0,0);
  // 7. layer-2 adjacency collapsed (sg via coalesced MFMA GEMV, N=2)
  wgemm_k<19,0,0><<<dim3(128,1,1),256,0,stream>>>(g1b,w12,nullptr,sgi, 2,2,2, 0,0,0);
  adjsum2_k<<<4096,256,0,stream>>>(whs,sgi,sbx,adjs);
  // 8. GCN layer 2
  tr_k<<<dim3(10,2,BB),256,0,stream>>>(g1b,g1t);
  wgemm_k<4,0,1><<<dim3(2,4,BB),256,0,stream>>>(adjs,g1t,nullptr,ax2b, DM,DMP,DMP, 16384,(long long)DMP*NN_,(long long)NN_*DMP);
  wgemm_k<19,1,1><<<dim3(128,8,1),256,0,stream>>>(ax2b,wwp,bw,g2b, DM,DMP,DMP, 0,0,0);
  // 9. head (bf16 hnode out)
  wgemm_k<19,2,1><<<dim3(128,4,1),256,0,stream>>>(g2b,wxxp,bxx,hnb, RHID,RHID,RHID, 0,0,0);
  pooled_k<<<BB,320,0,stream>>>(hnb,mask,Wc,bc,out);
}

// Round 14
// 1203.377 us; speedup vs baseline: 1.1061x; 1.1061x over previous
//
#include <hip/hip_runtime.h>
#include <math.h>

// ---- problem constants ----
#define BB    64
#define NN_   128
#define NH    6
#define DM    600     // d_model
#define RHID  300     // rnn hidden
#define DKH   100     // per-head dim
#define INDIM 360
#define G4    1200    // 4*RHID
#define WXROW 1206    // NH + 2*DM
#define DMP   608     // DM padded to mult of 32
#define INP   384     // INDIM padded
#define QKL   1536    // 2 * NH * 128 (head-padded q||k row length)
#define XGW   2400    // merged xg row width (fwd 0:1200, bwd 1200:2400)

// ---- LSTM cluster config (R10: REVERT to R8-measured best: 25 thin clusters) ----
// R9 regression (700us vs 575us) proved per-thread serial work per step is the
// scaling cost on top of a fixed ~8k cy sync floor; 3 tiles/thread is the sweet
// spot measured so far.
#define S_CL  25
#define NSU   12
#define NSR   48
#define KPAD  320
#define HSLOT (BB*KPAD)          // 20480 bf16 per history slot
#define DSTR  (129*HSLOT)        // per-dir history stride (bf16)

// R8 measured: AGENT == SYSTEM on gfx950 (per-XCD L2 non-coherent -> agent
// coherence point is also MALL).
#define COMM_SCOPE __HIP_MEMORY_SCOPE_AGENT

// ---- workspace layout (float offsets). Peak ~ 26.35M fl = 105.4 MB ----
#define OFF_GINB   0ull                 // bf16 [8192][608] = 2,490,368 fl
#define OFF_ASPECT 2490368ull
#define OFF_ASCB   2573568ull
#define OFF_W1SUM  2622720ull
#define OFF_W2SUM  2623360ull
#define OFF_SWX    2624000ull
#define OFF_SBX    2624016ull
#define OFF_SGI    2624032ull           // fp32 [8192][2] interleaved (sg1,sg2)
#define OFF_WHS    2640416ull           // fp32 [64][128][128]
#define OFF_WQKP   3688992ull           // bf16 [1536][608] = 466,944 fl
#define OFF_BQK    4155936ull           // fp32 1536
#define OFF_WWP    4157472ull           // bf16 [600][608] = 182,400 fl
#define OFF_WXXP   4339872ull           // bf16 [300][608] = 91,200 fl
#define OFF_WIHP   4431072ull           // bf16 [2400][384] = 460,800 fl
#define OFF_BP     4891872ull           // fp32 [2400]
#define OFF_WTB    4894272ull           // bf16 [2][1200][320] = 384,000 fl
#define OFF_EMBS   5278272ull           // bf16 [8192][384] = 1,572,864 fl
#define ARENA      6851136ull
#define OFF_XG     (ARENA)                      // bf16 [8192][2400] = 9,830,400 fl
#define OFF_HIST   (ARENA + 9830400ull)         // bf16 [2][129][64][320] = 2,641,920 fl
#define OFF_FLAGS  (ARENA + 12472320ull)        // flags (50, 128B apart)
// post-lstm reuse (xg dead after lstm; hist/flags dead after lstm):
#define OFF_QKH    (ARENA)                      // bf16 [8192][1536] = 6,291,456 fl (over xg)
#define OFF_ADJ    (ARENA + 6291456ull)         // bf16 [64][6][128][128] = 3,145,728 fl
#define OFF_ADJS   (ARENA + 16121856ull)        // bf16 [64][128][128] = 524,288 fl
#define OFF_GINT   (ARENA + 16646144ull)        // bf16 [64][608][128] = 2,490,368 fl
#define OFF_W12    (ARENA + 19136512ull)        // bf16 [2][608] = 608 fl
#define OFF_WDM    (ARENA + 19137152ull)        // fp32 [6][600][100] = 360,000 fl
#define OFF_BDM    (ARENA + 19497152ull)        // fp32 600
#define OFF_AXB    (ARENA)                      // bf16 (over qkh, dead after attn2/ascf)
#define OFF_G1B    (ARENA + 2490368ull)
#define OFF_G1T    (OFF_GINT)
#define OFF_AX2B   (ARENA + 4980736ull)
#define OFF_G2B    (ARENA + 7471104ull)         // over adj (dead after adjsum)
#define OFF_HNB    (ARENA + 9961472ull)         // bf16 [8192][300] (over hist, dead)

// ---- pack_k segmented index space ----
#define PK0 (XGW*INP + XGW)                 //   924,000 wihp + bias
#define PK1 (PK0 + QKL*DMP + QKL)           // 1,859,424 wqkhp + bias
#define PK2 (PK1 + DM*DMP)                  // 2,224,224 Ww pack
#define PK3 (PK2 + RHID*DMP)                // 2,406,624 Wxx pack
#define PK4 (PK3 + 2*G4*KPAD)               // 3,174,624 Whh both dirs
#define PK5 (PK4 + 22528)                   // 3,197,152 hist slot0 + flags init
#define PK6 (PK5 + 32768)                   // 3,229,920 ginb pad cols [600,608) = 0

typedef __bf16 bf16x8 __attribute__((ext_vector_type(8)));
typedef __bf16 bf16x4 __attribute__((ext_vector_type(4)));
typedef __bf16 bf16x2 __attribute__((ext_vector_type(2)));
typedef float  f32x4  __attribute__((ext_vector_type(4)));

__device__ __forceinline__ float sigm(float x){ return 1.f/(1.f+__expf(-x)); }
// Fast tanh (R10): 2*sigm(2x)-1 form; saturates gracefully to +/-1 at extremes
// (expf(-inf)=0, expf(+inf)=inf -> 2/inf=0), NaN-free, 1 trans + 1 rcp vs the
// branchy library tanhf. bf16 storage (0.4% quanta) swamps the ~1e-7 approx err.
__device__ __forceinline__ float tanh_f(float x){
  return 2.f/(1.f+__expf(-2.f*x)) - 1.f;
}
__device__ __forceinline__ float selu_f(float x){
  const float sc=1.0507009873554805f, al=1.6732632423543772f;
  return x>0.f ? sc*x : sc*al*(__expf(x)-1.f);
}
__device__ __forceinline__ bf16x8 bzero8(){
  bf16x8 z;
#pragma unroll
  for (int j=0;j<8;++j) z[j]=(__bf16)0.f;
  return z;
}

// ---------------- embedding concat -> bf16 [8192][384], pads written zero ----------------
__global__ __launch_bounds__(384) void embed_k(
    const int* __restrict__ tok, const int* __restrict__ pos_ids, const int* __restrict__ post_ids,
    const float* __restrict__ emb_w, const float* __restrict__ pos_w, const float* __restrict__ post_w,
    __bf16* __restrict__ embs)
{
  int bn = blockIdx.x, t = threadIdx.x;
  float v = 0.f;
  if      (t < 300) v = emb_w [(size_t)tok     [bn]*300 + t];
  else if (t < 330) v = pos_w [(size_t)pos_ids [bn]*30  + (t-300)];
  else if (t < 360) v = post_w[(size_t)post_ids[bn]*30  + (t-330)];
  embs[(size_t)bn*INP + t] = (__bf16)v;
}

// ---------------- Wx folded constants (+ bf16 w12 for the sg GEMV) ----------------
__global__ __launch_bounds__(640) void consts_k(
    const float* __restrict__ Wx, const float* __restrict__ bx,
    float* __restrict__ w1sum, float* __restrict__ w2sum,
    float* __restrict__ swx, float* __restrict__ sbx, __bf16* __restrict__ w12)
{
  int t = threadIdx.x;
  if (t < DM){
    float s1=0.f, s2=0.f;
    for (int k=0;k<NH;++k){ s1 += Wx[k*WXROW + NH + t]; s2 += Wx[k*WXROW + NH + DM + t]; }
    w1sum[t]=s1; w2sum[t]=s2;
    w12[t]=(__bf16)s1; w12[DMP+t]=(__bf16)s2;
  } else if (t < DM+NH){
    int h=t-DM; float s=0.f;
    for (int k=0;k<NH;++k) s += Wx[k*WXROW + h];
    swx[h]=s;
  } else if (t == DM+NH){
    float s=0.f; for (int k=0;k<NH;++k) s += bx[k];
    sbx[0]=s;
  }
  if (t >= DM && t < DMP){ w12[t]=(__bf16)0.f; w12[DMP+t]=(__bf16)0.f; }
}

// ---------------- WdM[h][D][e] = sum_d Wd[d][D]*wm[h][d][e]; bdM[h][e] = bd·wm[h][:,e] ----------------
__global__ __launch_bounds__(128) void wdm_k(
    const float* __restrict__ Wd, const float* __restrict__ bd, const float* __restrict__ wm,
    float* __restrict__ WdM, float* __restrict__ bdM)
{
  int D = blockIdx.x, h = blockIdx.y, e = threadIdx.x;
  if (e >= DKH) return;
  float s = 0.f;
  for (int d=0; d<DKH; ++d)
    s += Wd[d*DM + D] * wm[(h*DKH+d)*DKH + e];
  WdM[((size_t)h*DM + D)*DKH + e] = s;
  if (D == 0){
    float sb = 0.f;
    for (int d=0; d<DKH; ++d) sb += bd[d]*wm[(h*DKH+d)*DKH + e];
    bdM[h*DKH + e] = sb;
  }
}

// ---------------- fused packing/init (segmented): wihp|wqkhp|Ww|Wxx|Whh|init|ginb-pads ----------------
__global__ __launch_bounds__(256) void pack_k(
    const float* __restrict__ Wih_f, const float* __restrict__ b_f,
    const float* __restrict__ Wih_b, const float* __restrict__ b_b,
    const float* __restrict__ Wq, const float* __restrict__ bq,
    const float* __restrict__ Wk, const float* __restrict__ bk,
    const float* __restrict__ Ww, const float* __restrict__ Wxx,
    const float* __restrict__ Whh_f, const float* __restrict__ Whh_b,
    __bf16* __restrict__ wihp, float* __restrict__ bp,
    __bf16* __restrict__ wqkp, float* __restrict__ bqk,
    __bf16* __restrict__ wwp, __bf16* __restrict__ wxxp,
    __bf16* __restrict__ wtb, float* __restrict__ ws)
{
  int idx = blockIdx.x*256 + threadIdx.x;
  if (idx < PK0){
    if (idx < XGW*INP){
      int r = idx / INP, k = idx - r*INP;
      int dir = r >= G4; int p = r - dir*G4;
      const float* W = dir ? Wih_b : Wih_f;
      int srow = (p&3)*RHID + (p>>2);
      wihp[idx] = (k<INDIM) ? (__bf16)W[(size_t)srow*INDIM + k] : (__bf16)0.f;
    } else {
      int n = idx - XGW*INP;
      int dir = n >= G4; int p = n - dir*G4;
      const float* b = dir ? b_b : b_f;
      bp[n] = b[(p&3)*RHID + (p>>2)];
    }
  } else if (idx < PK1){
    int id = idx - PK0;
    if (id < QKL*DMP){
      int n = id / DMP, k = id - n*DMP;
      int nl = (n < 768) ? n : n - 768;
      int h = nl >> 7, e = nl & 127;
      float v = 0.f;
      if (k < DM && e < DKH)
        v = (n < 768) ? Wq[(size_t)(h*DKH+e)*DM + k] : Wk[(size_t)(h*DKH+e)*DM + k];
      wqkp[id] = (__bf16)v;
    } else {
      int n = id - QKL*DMP;
      int nl = (n < 768) ? n : n - 768;
      int h = nl >> 7, e = nl & 127;
      bqk[n] = (e < DKH) ? ((n < 768) ? bq[h*DKH+e] : bk[h*DKH+e]) : 0.f;
    }
  } else if (idx < PK2){
    int id = idx - PK1;
    int n = id / DMP, k = id - n*DMP;
    wwp[id] = (k < DM) ? (__bf16)Ww[(size_t)n*DM + k] : (__bf16)0.f;
  } else if (idx < PK3){
    int id = idx - PK2;
    int n = id / DMP, k = id - n*DMP;
    wxxp[id] = (k < DM) ? (__bf16)Wxx[(size_t)n*DM + k] : (__bf16)0.f;
  } else if (idx < PK4){
    int id = idx - PK3;
    int dir = id >= G4*KPAD; int id2 = id - dir*G4*KPAD;
    int p = id2 / KPAD, k = id2 - p*KPAD;
    const float* Whh = dir ? Whh_b : Whh_f;
    wtb[id] = (k < RHID) ? (__bf16)Whh[((size_t)((p&3)*RHID + (p>>2)))*RHID + k] : (__bf16)0.f;
  } else if (idx < PK5){
    int id = idx - PK4;
    if (id < 10240)      ws[OFF_HIST + id] = 0.f;                        // dir0 slot0
    else if (id < 20480) ws[OFF_HIST + 1320960ull + (id-10240)] = 0.f;   // dir1 slot0
    else                 ws[OFF_FLAGS + (id-20480)] = 0.f;               // flags
  } else if (idx < PK6){
    // ginb pad cols [600,608) = 0 (lstm epilogue writes only [0,600))
    int id = idx - PK5;
    ((unsigned*)ws)[(size_t)(id>>2)*(DMP/2) + (DM/2) + (id&3)] = 0u;
  }
}

// ---------------- LDS-free bf16 MFMA GEMM: C = act(A @ B^T + bias) ----------------
// Dual accumulator chains (even/odd kt) double per-wave MFMA ILP.
template<int KT, int ACT, int OBF>
__global__ __launch_bounds__(256) void wgemm_k(
    const __bf16* __restrict__ A, const __bf16* __restrict__ B,
    const float* __restrict__ bias, void* __restrict__ Cout,
    int Nn, int Npad, int ldc,
    long long sA, long long sB, long long sC)
{
  const int tid = threadIdx.x, lane = tid & 63, wave = tid >> 6;
  const int fn = lane & 15, fq = lane >> 4;
  const int K = KT*32;
  const __bf16* Ab = A + (size_t)blockIdx.z * (size_t)sA;
  const __bf16* Bb = B + (size_t)blockIdx.z * (size_t)sB;
  float*  Cf = (float*) Cout + (size_t)blockIdx.z * (size_t)sC;
  __bf16* Ch = (__bf16*)Cout + (size_t)blockIdx.z * (size_t)sC;

  const int m0 = (blockIdx.x*4 + wave)*16;

  bf16x8 Af[KT];
#pragma unroll
  for (int kt=0; kt<KT; ++kt)
    Af[kt] = *(const bf16x8*)(Ab + (size_t)(m0 + fn)*K + kt*32 + fq*8);

  for (int n0 = blockIdx.y*16; n0 < Nn; n0 += 16*gridDim.y){
    const int gn = n0 + fn;
    const int gnc = (gn < Nn) ? gn : 0;
    f32x4 acc0 = {0.f,0.f,0.f,0.f};
    f32x4 acc1 = {0.f,0.f,0.f,0.f};
#pragma unroll
    for (int kt=0; kt<KT; ++kt){
      bf16x8 Bf = *(const bf16x8*)(Bb + (size_t)gnc*K + kt*32 + fq*8);
      if (gn >= Nn) Bf = bzero8();
      if (kt & 1) acc1 = __builtin_amdgcn_mfma_f32_16x16x32_bf16(Af[kt], Bf, acc1, 0, 0, 0);
      else        acc0 = __builtin_amdgcn_mfma_f32_16x16x32_bf16(Af[kt], Bf, acc0, 0, 0, 0);
    }
    float bv = (bias && gn < Nn) ? bias[gn] : 0.f;
#pragma unroll
    for (int r=0; r<4; ++r){
      int gm = m0 + fq*4 + r;
      float v = acc0[r] + acc1[r] + bv;
      if (ACT==1) v = selu_f(v);
      else if (ACT==2) v = fmaxf(v, 0.f);
      if (gn < Nn){
        if (OBF) Ch[(size_t)gm*ldc + gn] = (__bf16)v;
        else     Cf[(size_t)gm*ldc + gn] = v;
      } else if (gn < Npad){
        if (OBF) Ch[(size_t)gm*ldc + gn] = (__bf16)0.f;
        else     Cf[(size_t)gm*ldc + gn] = 0.f;
      }
    }
  }
}

// ---------------- bf16 per-batch transpose [64][128][608] -> [64][608][128] ----------------
__global__ __launch_bounds__(256) void tr_k(
    const __bf16* __restrict__ in, __bf16* __restrict__ out)
{
  const int b = blockIdx.z, m0 = blockIdx.y*64, d0 = blockIdx.x*64;
  const int tid = threadIdx.x;
  __shared__ __align__(16) __bf16 T[64][72];
  const __bf16* ib = in + (size_t)b*NN_*DMP;
  __bf16* ob = out + (size_t)b*DMP*NN_;
#pragma unroll
  for (int r=0;r<2;++r){
    int idx = tid + 256*r;
    int mi = idx>>3, ch = idx&7;
    int d = d0 + ch*8;
    bf16x8 v = bzero8();
    if (d < DMP) v = *(const bf16x8*)(ib + (size_t)(m0+mi)*DMP + d);
    *(bf16x8*)&T[mi][ch*8] = v;
  }
  __syncthreads();
#pragma unroll
  for (int r=0;r<2;++r){
    int idx = tid + 256*r;
    int di = idx>>3, mch = idx&7;
    int d = d0 + di;
    if (d >= DMP) continue;
    bf16x8 v;
#pragma unroll
    for (int j=0;j<8;++j) v[j] = T[mch*8+j][di];
    *(bf16x8*)(ob + (size_t)d*NN_ + m0 + mch*8) = v;
  }
}

// ---------------- cooperative-cluster MFMA LSTM — R10: R8-measured geometry + fast tanh ----
// R8 config (25 thin clusters/dir, NTL=3, dual staggered pollers) measured 575us.
// R9 (fat clusters) regressed to 700us: per-thread serial work scales the step.
// R10 keeps R8 geometry; only change is tanh_f (1 trans) replacing library tanhf
// (branchy) in the 6 calls/thread/step of the serial epilogue.
__global__ __launch_bounds__(256, 1) void lstm_mfma_k(
    const __bf16* __restrict__ xg,
    const __bf16* __restrict__ wtb,
    __bf16* hist, int* flags,
    __bf16* __restrict__ ginb,
    const float* __restrict__ mask, float* __restrict__ aspect)
{
  const int blk = blockIdx.x;
  const int dir = blk / S_CL, sl = blk - dir*S_CL;
  const int tid = threadIdx.x, lane = tid & 63, wave = tid >> 6;
  const int p0 = sl * NSR;
  const __bf16* W = wtb + (size_t)dir * G4 * KPAD;
  __bf16* hb = hist + (size_t)dir * DSTR;

  const int fn = lane & 15, fq = lane >> 4, fk = fq*8;
  const int b  = wave*16 + fn;

  __shared__ volatile int done_s;
  __shared__ float mskL[NN_*BB];        // [n][b] transposed, 32 KB
  if (tid == 0) done_s = 0;
  for (int i = tid; i < BB*NN_; i += 256){
    int bb = i >> 7, nn = i & 127;
    mskL[nn*BB + bb] = mask[i];
  }

  bf16x8 Wf[3][10];
#pragma unroll
  for (int nt = 0; nt < 3; ++nt)
#pragma unroll
    for (int kt = 0; kt < 10; ++kt)
      Wf[nt][kt] = *(const bf16x8*)(W + (size_t)(p0 + nt*16 + fn)*KPAD + kt*32 + fk);

  float cst[3] = {0.f,0.f,0.f};
  float asp[3] = {0.f,0.f,0.f};
  float wnacc  = 0.f;
  const __bf16* xb = xg + (size_t)b*NN_*XGW + dir*G4 + p0 + fq*4;
  const int u0 = sl*NSU + fq;                 // + nt*4 -> unit in [0,300)
  __syncthreads();

  for (int s = 0; s < NN_; ++s){
    const int n_t = dir ? (NN_-1-s) : s;
    const __bf16* hbr = hb + (size_t)s*HSLOT + (size_t)b*KPAD;
    __bf16*       hbw = hb + (size_t)(s+1)*HSLOT + (size_t)b*KPAD;

    unsigned long long xv[3];
#pragma unroll
    for (int nt = 0; nt < 3; ++nt)
      xv[nt] = *(const unsigned long long*)(xb + (size_t)n_t*XGW + nt*16);
    const float mval = mskL[n_t*BB + b];

    bf16x8 Hf[10];
#pragma unroll
    for (int kt = 0; kt < 10; ++kt){
      const unsigned long long* hp = (const unsigned long long*)(hbr + kt*32 + fk);
      union { unsigned long long u[2]; bf16x8 v; } cv;
      cv.u[0] = __hip_atomic_load(hp,   __ATOMIC_RELAXED, COMM_SCOPE);
      cv.u[1] = __hip_atomic_load(hp+1, __ATOMIC_RELAXED, COMM_SCOPE);
      Hf[kt] = cv.v;
    }

    f32x4 acc[3] = { {0.f,0.f,0.f,0.f},{0.f,0.f,0.f,0.f},{0.f,0.f,0.f,0.f} };
#pragma unroll
    for (int kt = 0; kt < 10; ++kt)
#pragma unroll
      for (int nt = 0; nt < 3; ++nt)
        acc[nt] = __builtin_amdgcn_mfma_f32_16x16x32_bf16(Wf[nt][kt], Hf[kt], acc[nt], 0, 0, 0);

    __bf16 hsv[3];
#pragma unroll
    for (int nt = 0; nt < 3; ++nt){
      union { unsigned long long u; __bf16 g[4]; } xu; xu.u = xv[nt];
      float ig = sigm  (acc[nt][0] + (float)xu.g[0]);
      float fg = sigm  (acc[nt][1] + (float)xu.g[1]);
      float gg = tanh_f(acc[nt][2] + (float)xu.g[2]);
      float og = sigm  (acc[nt][3] + (float)xu.g[3]);
      float c = fg*cst[nt] + ig*gg; cst[nt] = c;
      float hval = og * tanh_f(c);
      asp[nt] += hval * mval;
      union { unsigned short us; __bf16 h; } pk; pk.h = (__bf16)hval;
      hsv[nt] = pk.h;
      // hist store MUST precede the flag -> stays in the pre-barrier drain.
      __hip_atomic_store((unsigned short*)(hbw + u0 + nt*4), pk.us,
                         __ATOMIC_RELAXED, COMM_SCOPE);
    }
    wnacc += mval;

    __syncthreads();   // drains hist stores (vmcnt0) before flag release
    if (tid == 0)
      __hip_atomic_store(&flags[(dir*S_CL + sl)*32], s+1,
                         __ATOMIC_RELAXED, COMM_SCOPE);
    // Deferred ginb stores: issued after flag; their drain overlaps poll/next-step
    // latency (they complete by the next iteration's __syncthreads).
#pragma unroll
    for (int nt = 0; nt < 3; ++nt)
      ginb[(size_t)(b*NN_ + n_t)*DMP + dir*RHID + u0 + nt*4] = hsv[nt];
    if (wave < 2){
      if (wave == 1) __builtin_amdgcn_s_sleep(2);   // phase-offset the second poller
      int* fp = &flags[(dir*S_CL + (lane < S_CL ? lane : 0))*32];
      bool ok = (lane >= S_CL);
      while (done_s < s+1){
        if (!ok) ok = (__hip_atomic_load(fp, __ATOMIC_RELAXED, COMM_SCOPE) >= s+1);
        if (__all((int)ok)){ done_s = s+1; break; }
      }
    }
    __syncthreads();
  }

  const float invwn = 1.f / wnacc;
#pragma unroll
  for (int nt = 0; nt < 3; ++nt)
    aspect[b*DM + dir*RHID + u0 + nt*4] = asp[nt]*invwn;
}

// ---------------- fused: aw = aspect@WdM + bdM ; asc = tanh(aw·k + bias_m) ----------------
__global__ __launch_bounds__(128) void ascf_k(
    const float* __restrict__ aspect, const float* __restrict__ WdM, const float* __restrict__ bdM,
    const __bf16* __restrict__ qkh, const float* __restrict__ bias_m, float* __restrict__ asc)
{
  int b = blockIdx.x, h = blockIdx.y, t = threadIdx.x;
  __shared__ __align__(16) float asp[DM];
  __shared__ __align__(16) float awl[DKH];
  for (int i = t; i < DM; i += 128) asp[i] = aspect[b*DM + i];
  __syncthreads();
  if (t < DKH){
    const float* wrow = WdM + (size_t)h*DM*DKH + t;
    float s0=0.f,s1=0.f,s2=0.f,s3=0.f;
    for (int D=0; D<DM; D+=4){
      s0 += asp[D+0]*wrow[(size_t)(D+0)*DKH];
      s1 += asp[D+1]*wrow[(size_t)(D+1)*DKH];
      s2 += asp[D+2]*wrow[(size_t)(D+2)*DKH];
      s3 += asp[D+3]*wrow[(size_t)(D+3)*DKH];
    }
    awl[t] = s0+s1+s2+s3 + bdM[h*DKH + t];
  }
  __syncthreads();
  const __bf16* kr = qkh + (size_t)(b*NN_ + t)*QKL + 768 + h*128;
  float s=0.f;
#pragma unroll
  for (int e=0;e<DKH;e+=2){
    bf16x2 kv = *(const bf16x2*)(kr + e);
    s += awl[e]*(float)kv[0] + awl[e+1]*(float)kv[1];
  }
  asc[(b*NH+h)*NN_ + t] = tanhf(s + bias_m[0]);
}

// ---------------- MFMA attention (split x2): scores + mask + short + softmax -> adj bf16 ----------------
__global__ __launch_bounds__(256) void attn2_k(
    const __bf16* __restrict__ qkh, const float* __restrict__ asc,
    const float* __restrict__ shortm, const int* __restrict__ tok,
    __bf16* __restrict__ adj)
{
  const int bx = blockIdx.x;
  const int bh = bx >> 1, half = bx & 1;
  const int b = bh / NH, h = bh - b*NH;
  const int tid = threadIdx.x, lane = tid & 63, wave = tid >> 6;
  const int fn = lane & 15, fq = lane >> 4;
  const __bf16* qb = qkh + (size_t)(b*NN_)*QKL + h*128;
  const __bf16* kb = qkh + (size_t)(b*NN_)*QKL + 768 + h*128;

  const int m0 = half*64 + wave*16;
  bf16x8 Af[4];
#pragma unroll
  for (int kt=0;kt<4;++kt)
    Af[kt] = *(const bf16x8*)(qb + (size_t)(m0+fn)*QKL + kt*32 + fq*8);

  f32x4 acc[8];
#pragma unroll
  for (int j=0;j<8;++j) acc[j] = (f32x4){0.f,0.f,0.f,0.f};

#pragma unroll
  for (int j=0;j<8;++j){
    bf16x8 Bf[4];
#pragma unroll
    for (int kt=0;kt<4;++kt)
      Bf[kt] = *(const bf16x8*)(kb + (size_t)(j*16+fn)*QKL + kt*32 + fq*8);
#pragma unroll
    for (int kt=0;kt<4;++kt)
      acc[j] = __builtin_amdgcn_mfma_f32_16x16x32_bf16(Af[kt], Bf[kt], acc[j], 0,0,0);
  }

  float ascv[8]; int msk[8];
#pragma unroll
  for (int j=0;j<8;++j){
    int c = j*16 + fn;
    ascv[j] = asc[(b*NH+h)*NN_ + c];
    msk [j] = tok[b*NN_ + c];
  }

#pragma unroll
  for (int r=0;r<4;++r){
    int m = m0 + fq*4 + r;
    float sv[8];
#pragma unroll
    for (int j=0;j<8;++j){
      int c = j*16 + fn;
      float s = acc[j][r]*0.1f + ascv[j];
      if (msk[j]==0) s = -1e9f;
      s += shortm[((size_t)(b*NN_+m))*NN_ + c];
      sv[j]=s;
    }
    float mx = sv[0];
#pragma unroll
    for (int j=1;j<8;++j) mx = fmaxf(mx, sv[j]);
#pragma unroll
    for (int o=1;o<16;o<<=1) mx = fmaxf(mx, __shfl_xor(mx, o, 64));
    float sum = 0.f, ev[8];
#pragma unroll
    for (int j=0;j<8;++j){ ev[j]=__expf(sv[j]-mx); sum+=ev[j]; }
#pragma unroll
    for (int o=1;o<16;o<<=1) sum += __shfl_xor(sum, o, 64);
    float inv = 1.f/sum;
#pragma unroll
    for (int j=0;j<8;++j)
      adj[(((size_t)(b*NH+h))*NN_ + m)*NN_ + j*16 + fn] = (__bf16)(ev[j]*inv);
  }
}

// ---------------- adjsum (bf16 in) -> bf16 adjs (/H) + fp32 whs ----------------
__global__ __launch_bounds__(256) void adjsum_k(
    const __bf16* __restrict__ adj, const float* __restrict__ swx,
    __bf16* __restrict__ adjs, float* __restrict__ whs)
{
  int idx = blockIdx.x*256 + threadIdx.x;
  int b = idx >> 14, rem = idx & 16383;
  float s=0.f, w=0.f;
  for (int h=0;h<NH;++h){
    float v = (float)adj[(((size_t)b*NH+h)<<14) + rem];
    s += v; w += v*swx[h];
  }
  adjs[idx] = (__bf16)(s*(1.f/NH));
  whs [idx] = w*(1.f/NH);
}

// ---------------- adjs2[b,i,j] = whs + (sg1[b,j]+sg2[b,i]+sbx)/H -> bf16 ----------------
__global__ __launch_bounds__(256) void adjsum2_k(
    const float* __restrict__ whs, const float* __restrict__ sgi,
    const float* __restrict__ sbx, __bf16* __restrict__ adjs)
{
  int idx = blockIdx.x*256 + threadIdx.x;
  int b = idx >> 14, rem = idx & 16383;
  int i = rem >> 7, j = rem & 127;
  adjs[idx] = (__bf16)(whs[idx] + (sgi[(b*NN_+j)*2] + sgi[(b*NN_+i)*2+1] + sbx[0])*(1.f/NH));
}

// ---------------- pooled mean + logits (bf16 hn) ----------------
__global__ __launch_bounds__(320) void pooled_k(
    const __bf16* __restrict__ hn, const float* __restrict__ mask,
    const float* __restrict__ Wc, const float* __restrict__ bc, float* __restrict__ out)
{
  int b=blockIdx.x, t=threadIdx.x;
  __shared__ float msk[NN_];
  __shared__ float pl[RHID];
  __shared__ float wn;
  if (t<NN_) msk[t]=mask[b*NN_+t];
  __syncthreads();
  if (t==0){ float s=0.f; for (int n=0;n<NN_;++n) s+=msk[n]; wn=s; }
  __syncthreads();
  if (t<RHID){
    float s=0.f;
    for (int n=0;n<NN_;++n) s += (float)hn[((size_t)(b*NN_+n))*RHID+t]*msk[n];
    pl[t]=s/wn;
  }
  __syncthreads();
  if (t<3){
    float s=bc[t];
    for (int d=0;d<RHID;++d) s += pl[d]*Wc[t*RHID+d];
    out[b*3+t]=s;
  }
}

extern "C" void kernel_launch(void* const* d_in, const int* in_sizes, int n_in,
                              void* d_out, int out_size, void* d_ws, size_t ws_size,
                              hipStream_t stream)
{
  (void)in_sizes; (void)n_in; (void)out_size; (void)ws_size;
  const int*   tok      = (const int*)  d_in[0];
  const int*   pos_ids  = (const int*)  d_in[2];
  const int*   post_ids = (const int*)  d_in[5];
  const float* mask     = (const float*)d_in[6];
  const float* shortm   = (const float*)d_in[8];
  const float* emb_w    = (const float*)d_in[9];
  const float* pos_w    = (const float*)d_in[10];
  const float* post_w   = (const float*)d_in[11];
  const float* Wih_f    = (const float*)d_in[12];
  const float* Whh_f    = (const float*)d_in[13];
  const float* b_f      = (const float*)d_in[14];
  const float* Wih_b    = (const float*)d_in[15];
  const float* Whh_b    = (const float*)d_in[16];
  const float* b_b      = (const float*)d_in[17];
  const float* Wq       = (const float*)d_in[18];
  const float* bq       = (const float*)d_in[19];
  const float* Wk       = (const float*)d_in[20];
  const float* bk       = (const float*)d_in[21];
  const float* Wd       = (const float*)d_in[22];
  const float* bd       = (const float*)d_in[23];
  const float* weight_m = (const float*)d_in[24];
  const float* bias_m   = (const float*)d_in[25];
  const float* Ww       = (const float*)d_in[26];
  const float* bw       = (const float*)d_in[27];
  const float* Wx       = (const float*)d_in[28];
  const float* bx       = (const float*)d_in[29];
  const float* Wxx      = (const float*)d_in[30];
  const float* bxx      = (const float*)d_in[31];
  const float* Wc       = (const float*)d_in[32];
  const float* bc       = (const float*)d_in[33];

  float* ws  = (float*)d_ws;
  float* out = (float*)d_out;

  __bf16* ginb  = (__bf16*)(ws + OFF_GINB);
  float* aspect = ws + OFF_ASPECT;
  float* ascb   = ws + OFF_ASCB;
  float* w1sum  = ws + OFF_W1SUM;
  float* w2sum  = ws + OFF_W2SUM;
  float* swx    = ws + OFF_SWX;
  float* sbx    = ws + OFF_SBX;
  float* sgi    = ws + OFF_SGI;
  float* whs    = ws + OFF_WHS;
  __bf16* wqkp  = (__bf16*)(ws + OFF_WQKP);
  float* bqk    = ws + OFF_BQK;
  __bf16* wwp   = (__bf16*)(ws + OFF_WWP);
  __bf16* wxxp  = (__bf16*)(ws + OFF_WXXP);
  __bf16* wihp  = (__bf16*)(ws + OFF_WIHP);
  float* bp     = ws + OFF_BP;
  __bf16* wtb   = (__bf16*)(ws + OFF_WTB);
  __bf16* embs  = (__bf16*)(ws + OFF_EMBS);
  __bf16* xg    = (__bf16*)(ws + OFF_XG);
  __bf16* hist  = (__bf16*)(ws + OFF_HIST);
  int*   flags  = (int*)(ws + OFF_FLAGS);
  __bf16* qkh   = (__bf16*)(ws + OFF_QKH);
  __bf16* adjb  = (__bf16*)(ws + OFF_ADJ);
  __bf16* adjs  = (__bf16*)(ws + OFF_ADJS);
  __bf16* gint  = (__bf16*)(ws + OFF_GINT);
  __bf16* w12   = (__bf16*)(ws + OFF_W12);
  float* wdm    = ws + OFF_WDM;
  float* bdm    = ws + OFF_BDM;
  __bf16* axb   = (__bf16*)(ws + OFF_AXB);
  __bf16* g1b   = (__bf16*)(ws + OFF_G1B);
  __bf16* g1t   = (__bf16*)(ws + OFF_G1T);
  __bf16* ax2b  = (__bf16*)(ws + OFF_AX2B);
  __bf16* g2b   = (__bf16*)(ws + OFF_G2B);
  __bf16* hnb   = (__bf16*)(ws + OFF_HNB);

  // 1. embeddings, constants, fused packing/init (also zeroes ginb pad cols)
  embed_k<<<dim3(BB*NN_),384,0,stream>>>(tok,pos_ids,post_ids,emb_w,pos_w,post_w,embs);
  consts_k<<<1,640,0,stream>>>(Wx,bx,w1sum,w2sum,swx,sbx,w12);
  wdm_k<<<dim3(DM,NH),128,0,stream>>>(Wd,bd,weight_m,wdm,bdm);
  pack_k<<<dim3((PK6+255)/256),256,0,stream>>>(Wih_f,b_f,Wih_b,b_b,Wq,bq,Wk,bk,Ww,Wxx,
                                               Whh_f,Whh_b,wihp,bp,wqkp,bqk,wwp,wxxp,wtb,ws);
  // 2. merged LSTM input projection (both dirs), bf16 out [8192][2400]
  wgemm_k<12,0,1><<<dim3(128,8,1),256,0,stream>>>(embs,wihp,bp,xg, XGW,XGW,XGW, 0,0,0);
  // 3. recurrence — R10: R8-measured geometry (25 clusters/dir) + fast tanh.
  lstm_mfma_k<<<dim3(2*S_CL),256,0,stream>>>(xg,wtb,hist,flags,ginb,mask,aspect);
  // 4. fused Q||K projection (bf16 head-padded), aspect-biased scores input
  wgemm_k<19,0,1><<<dim3(128,12,1),256,0,stream>>>(ginb,wqkp,bqk,qkh, QKL,QKL,QKL, 0,0,0);
  ascf_k<<<dim3(BB,NH),128,0,stream>>>(aspect,wdm,bdm,qkh,bias_m,ascb);
  // 5. MFMA scores + softmax -> adj bf16
  attn2_k<<<dim3(BB*NH*2),256,0,stream>>>(qkh,ascb,shortm,tok,adjb);
  // 6. GCN layer 1 (bf16 MFMA)
  adjsum_k<<<4096,256,0,stream>>>(adjb,swx,adjs,whs);
  tr_k<<<dim3(10,2,BB),256,0,stream>>>(ginb,gint);
  wgemm_k<4,0,1><<<dim3(2,4,BB),256,0,stream>>>(adjs,gint,nullptr,axb, DM,DMP,DMP, 16384,(long long)DMP*NN_,(long long)NN_*DMP);
  wgemm_k<19,1,1><<<dim3(128,8,1),256,0,stream>>>(axb,wwp,bw,g1b, DM,DMP,DMP, 0,0,0);
  // 7. layer-2 adjacency collapsed (sg via coalesced MFMA GEMV, N=2)
  wgemm_k<19,0,0><<<dim3(128,1,1),256,0,stream>>>(g1b,w12,nullptr,sgi, 2,2,2, 0,0,0);
  adjsum2_k<<<4096,256,0,stream>>>(whs,sgi,sbx,adjs);
  // 8. GCN layer 2
  tr_k<<<dim3(10,2,BB),256,0,stream>>>(g1b,g1t);
  wgemm_k<4,0,1><<<dim3(2,4,BB),256,0,stream>>>(adjs,g1t,nullptr,ax2b, DM,DMP,DMP, 16384,(long long)DMP*NN_,(long long)NN_*DMP);
  wgemm_k<19,1,1><<<dim3(128,8,1),256,0,stream>>>(ax2b,wwp,bw,g2b, DM,DMP,DMP, 0,0,0);
  // 9. head (bf16 hnode out)
  wgemm_k<19,2,1><<<dim3(128,4,1),256,0,stream>>>(g2b,wxxp,bxx,hnb, RHID,RHID,RHID, 0,0,0);
  pooled_k<<<BB,320,0,stream>>>(hnb,mask,Wc,bc,out);
}

// Round 18
// 1115.573 us; speedup vs baseline: 1.1931x; 1.0787x over previous
//
#include <hip/hip_runtime.h>
#include <math.h>

// ---- problem constants ----
#define BB    64
#define NN_   128
#define NH    6
#define DM    600     // d_model
#define RHID  300     // rnn hidden
#define DKH   100     // per-head dim
#define INDIM 360
#define G4    1200    // 4*RHID
#define WXROW 1206    // NH + 2*DM
#define DMP   608     // DM padded to mult of 32
#define INP   384     // INDIM padded
#define QKL   1536    // 2 * NH * 128 (head-padded q||k row length)
#define XGW   2400    // merged xg row width (fwd 0:1200, bwd 1200:2400)

// ---- LSTM cluster config (R8-measured best: 25 thin clusters; at protocol floor) ----
#define S_CL  25
#define NSU   12
#define NSR   48
#define KPAD  320
#define HSLOT (BB*KPAD)          // 20480 bf16 per history slot
#define DSTR  (129*HSLOT)        // per-dir history stride (bf16)

#define COMM_SCOPE __HIP_MEMORY_SCOPE_AGENT

// ---- workspace layout (float offsets). Peak ~ 26.35M fl = 105.4 MB ----
#define OFF_GINB   0ull                 // bf16 [8192][608] = 2,490,368 fl
#define OFF_ASPECT 2490368ull
#define OFF_ASCB   2573568ull
#define OFF_W1SUM  2622720ull
#define OFF_W2SUM  2623360ull
#define OFF_SWX    2624000ull
#define OFF_SBX    2624016ull
#define OFF_SGI    2624032ull           // fp32 [8192][2] interleaved (sg1,sg2)
#define OFF_WHS    2640416ull           // fp32 [64][128][128]
#define OFF_WQKP   3688992ull           // bf16 [1536][608] = 466,944 fl
#define OFF_BQK    4155936ull           // fp32 1536
#define OFF_WWP    4157472ull           // bf16 [600][608] = 182,400 fl
#define OFF_WXXP   4339872ull           // bf16 [300][608] = 91,200 fl
#define OFF_WIHP   4431072ull           // bf16 [2400][384] = 460,800 fl
#define OFF_BP     4891872ull           // fp32 [2400]
#define OFF_WTB    4894272ull           // bf16 [2][1200][320] = 384,000 fl
#define OFF_EMBS   5278272ull           // bf16 [8192][384] = 1,572,864 fl
#define ARENA      6851136ull
#define OFF_XG     (ARENA)                      // bf16 [8192][2400] = 9,830,400 fl
#define OFF_HIST   (ARENA + 9830400ull)         // bf16 [2][129][64][320] = 2,641,920 fl
#define OFF_FLAGS  (ARENA + 12472320ull)        // flags (50, 128B apart)
// post-lstm reuse (xg dead after lstm; hist/flags dead after lstm):
#define OFF_QKH    (ARENA)                      // bf16 [8192][1536] = 6,291,456 fl (over xg)
#define OFF_ADJ    (ARENA + 6291456ull)         // bf16 [64][6][128][128] = 3,145,728 fl
#define OFF_ADJS   (ARENA + 16121856ull)        // bf16 [64][128][128] = 524,288 fl
#define OFF_GINT   (ARENA + 16646144ull)        // bf16 [64][608][128] = 2,490,368 fl
#define OFF_W12    (ARENA + 19136512ull)        // bf16 [2][608] = 608 fl
#define OFF_WDM    (ARENA + 19137152ull)        // fp32 [6][600][100] = 360,000 fl
#define OFF_BDM    (ARENA + 19497152ull)        // fp32 600
#define OFF_AXB    (ARENA)                      // bf16 (over qkh, dead after attn2/ascf)
#define OFF_G1B    (ARENA + 2490368ull)
#define OFF_G1T    (OFF_GINT)
#define OFF_AX2B   (ARENA + 4980736ull)
#define OFF_G2B    (ARENA + 7471104ull)         // over adj (dead after adjsum)
#define OFF_HNB    (ARENA + 9961472ull)         // bf16 [8192][300] (over hist, dead)

// ---- pack_k segmented index space ----
#define PK0 (XGW*INP + XGW)                 //   924,000 wihp + bias
#define PK1 (PK0 + QKL*DMP + QKL)           // 1,859,424 wqkhp + bias
#define PK2 (PK1 + DM*DMP)                  // 2,224,224 Ww pack
#define PK3 (PK2 + RHID*DMP)                // 2,406,624 Wxx pack
#define PK4 (PK3 + 2*G4*KPAD)               // 3,174,624 Whh both dirs
#define PK5 (PK4 + 22528)                   // 3,197,152 hist slot0 + flags init
#define PK6 (PK5 + 32768)                   // 3,229,920 ginb pad cols [600,608) = 0

typedef __bf16 bf16x8 __attribute__((ext_vector_type(8)));
typedef __bf16 bf16x4 __attribute__((ext_vector_type(4)));
typedef __bf16 bf16x2 __attribute__((ext_vector_type(2)));
typedef float  f32x4  __attribute__((ext_vector_type(4)));

__device__ __forceinline__ float sigm(float x){ return 1.f/(1.f+__expf(-x)); }
// Fast tanh (R14-measured neutral vs libm but cheaper in VGPR/issue; keep).
__device__ __forceinline__ float tanh_f(float x){
  return 2.f/(1.f+__expf(-2.f*x)) - 1.f;
}
__device__ __forceinline__ float selu_f(float x){
  const float sc=1.0507009873554805f, al=1.6732632423543772f;
  return x>0.f ? sc*x : sc*al*(__expf(x)-1.f);
}
__device__ __forceinline__ bf16x8 bzero8(){
  bf16x8 z;
#pragma unroll
  for (int j=0;j<8;++j) z[j]=(__bf16)0.f;
  return z;
}

// ---------------- embedding concat -> bf16 [8192][384], pads written zero ----------------
__global__ __launch_bounds__(384) void embed_k(
    const int* __restrict__ tok, const int* __restrict__ pos_ids, const int* __restrict__ post_ids,
    const float* __restrict__ emb_w, const float* __restrict__ pos_w, const float* __restrict__ post_w,
    __bf16* __restrict__ embs)
{
  int bn = blockIdx.x, t = threadIdx.x;
  float v = 0.f;
  if      (t < 300) v = emb_w [(size_t)tok     [bn]*300 + t];
  else if (t < 330) v = pos_w [(size_t)pos_ids [bn]*30  + (t-300)];
  else if (t < 360) v = post_w[(size_t)post_ids[bn]*30  + (t-330)];
  embs[(size_t)bn*INP + t] = (__bf16)v;
}

// ---------------- Wx folded constants (+ bf16 w12 for the sg GEMV) ----------------
__global__ __launch_bounds__(640) void consts_k(
    const float* __restrict__ Wx, const float* __restrict__ bx,
    float* __restrict__ w1sum, float* __restrict__ w2sum,
    float* __restrict__ swx, float* __restrict__ sbx, __bf16* __restrict__ w12)
{
  int t = threadIdx.x;
  if (t < DM){
    float s1=0.f, s2=0.f;
    for (int k=0;k<NH;++k){ s1 += Wx[k*WXROW + NH + t]; s2 += Wx[k*WXROW + NH + DM + t]; }
    w1sum[t]=s1; w2sum[t]=s2;
    w12[t]=(__bf16)s1; w12[DMP+t]=(__bf16)s2;
  } else if (t < DM+NH){
    int h=t-DM; float s=0.f;
    for (int k=0;k<NH;++k) s += Wx[k*WXROW + h];
    swx[h]=s;
  } else if (t == DM+NH){
    float s=0.f; for (int k=0;k<NH;++k) s += bx[k];
    sbx[0]=s;
  }
  if (t >= DM && t < DMP){ w12[t]=(__bf16)0.f; w12[DMP+t]=(__bf16)0.f; }
}

// ---------------- WdM[h][D][e] = sum_d Wd[d][D]*wm[h][d][e]; bdM[h][e] = bd·wm[h][:,e] ----------------
__global__ __launch_bounds__(128) void wdm_k(
    const float* __restrict__ Wd, const float* __restrict__ bd, const float* __restrict__ wm,
    float* __restrict__ WdM, float* __restrict__ bdM)
{
  int D = blockIdx.x, h = blockIdx.y, e = threadIdx.x;
  if (e >= DKH) return;
  float s = 0.f;
  for (int d=0; d<DKH; ++d)
    s += Wd[d*DM + D] * wm[(h*DKH+d)*DKH + e];
  WdM[((size_t)h*DM + D)*DKH + e] = s;
  if (D == 0){
    float sb = 0.f;
    for (int d=0; d<DKH; ++d) sb += bd[d]*wm[(h*DKH+d)*DKH + e];
    bdM[h*DKH + e] = sb;
  }
}

// ---------------- fused packing/init (segmented): wihp|wqkhp|Ww|Wxx|Whh|init|ginb-pads ----------------
__global__ __launch_bounds__(256) void pack_k(
    const float* __restrict__ Wih_f, const float* __restrict__ b_f,
    const float* __restrict__ Wih_b, const float* __restrict__ b_b,
    const float* __restrict__ Wq, const float* __restrict__ bq,
    const float* __restrict__ Wk, const float* __restrict__ bk,
    const float* __restrict__ Ww, const float* __restrict__ Wxx,
    const float* __restrict__ Whh_f, const float* __restrict__ Whh_b,
    __bf16* __restrict__ wihp, float* __restrict__ bp,
    __bf16* __restrict__ wqkp, float* __restrict__ bqk,
    __bf16* __restrict__ wwp, __bf16* __restrict__ wxxp,
    __bf16* __restrict__ wtb, float* __restrict__ ws)
{
  int idx = blockIdx.x*256 + threadIdx.x;
  if (idx < PK0){
    if (idx < XGW*INP){
      int r = idx / INP, k = idx - r*INP;
      int dir = r >= G4; int p = r - dir*G4;
      const float* W = dir ? Wih_b : Wih_f;
      int srow = (p&3)*RHID + (p>>2);
      wihp[idx] = (k<INDIM) ? (__bf16)W[(size_t)srow*INDIM + k] : (__bf16)0.f;
    } else {
      int n = idx - XGW*INP;
      int dir = n >= G4; int p = n - dir*G4;
      const float* b = dir ? b_b : b_f;
      bp[n] = b[(p&3)*RHID + (p>>2)];
    }
  } else if (idx < PK1){
    int id = idx - PK0;
    if (id < QKL*DMP){
      int n = id / DMP, k = id - n*DMP;
      int nl = (n < 768) ? n : n - 768;
      int h = nl >> 7, e = nl & 127;
      float v = 0.f;
      if (k < DM && e < DKH)
        v = (n < 768) ? Wq[(size_t)(h*DKH+e)*DM + k] : Wk[(size_t)(h*DKH+e)*DM + k];
      wqkp[id] = (__bf16)v;
    } else {
      int n = id - QKL*DMP;
      int nl = (n < 768) ? n : n - 768;
      int h = nl >> 7, e = nl & 127;
      bqk[n] = (e < DKH) ? ((n < 768) ? bq[h*DKH+e] : bk[h*DKH+e]) : 0.f;
    }
  } else if (idx < PK2){
    int id = idx - PK1;
    int n = id / DMP, k = id - n*DMP;
    wwp[id] = (k < DM) ? (__bf16)Ww[(size_t)n*DM + k] : (__bf16)0.f;
  } else if (idx < PK3){
    int id = idx - PK2;
    int n = id / DMP, k = id - n*DMP;
    wxxp[id] = (k < DM) ? (__bf16)Wxx[(size_t)n*DM + k] : (__bf16)0.f;
  } else if (idx < PK4){
    int id = idx - PK3;
    int dir = id >= G4*KPAD; int id2 = id - dir*G4*KPAD;
    int p = id2 / KPAD, k = id2 - p*KPAD;
    const float* Whh = dir ? Whh_b : Whh_f;
    wtb[id] = (k < RHID) ? (__bf16)Whh[((size_t)((p&3)*RHID + (p>>2)))*RHID + k] : (__bf16)0.f;
  } else if (idx < PK5){
    int id = idx - PK4;
    if (id < 10240)      ws[OFF_HIST + id] = 0.f;                        // dir0 slot0
    else if (id < 20480) ws[OFF_HIST + 1320960ull + (id-10240)] = 0.f;   // dir1 slot0
    else                 ws[OFF_FLAGS + (id-20480)] = 0.f;               // flags
  } else if (idx < PK6){
    // ginb pad cols [600,608) = 0 (lstm epilogue writes only [0,600))
    int id = idx - PK5;
    ((unsigned*)ws)[(size_t)(id>>2)*(DMP/2) + (DM/2) + (id&3)] = 0u;
  }
}

// ---------------- LDS-free bf16 MFMA GEMM: C = act(A @ B^T + bias) ----------------
// R15: MT-way M-blocking per wave. Each B fragment is reused for MT MFMAs
// (MFMA:B-load ratio MT:1 instead of 1:1) — attacks the measured ~628us
// non-LSTM stack, which is dominated by B-fragment VMEM/L2 traffic in these
// GEMMs (each wave re-loads every B fragment; B is L2-resident so HBM is
// fine but issue/L2 BW is the bottleneck). FP order per output unchanged.
template<int KT, int ACT, int OBF, int MT>
__global__ __launch_bounds__(256) void wgemm_k(
    const __bf16* __restrict__ A, const __bf16* __restrict__ B,
    const float* __restrict__ bias, void* __restrict__ Cout,
    int Nn, int Npad, int ldc,
    long long sA, long long sB, long long sC)
{
  const int tid = threadIdx.x, lane = tid & 63, wave = tid >> 6;
  const int fn = lane & 15, fq = lane >> 4;
  const int K = KT*32;
  const __bf16* Ab = A + (size_t)blockIdx.z * (size_t)sA;
  const __bf16* Bb = B + (size_t)blockIdx.z * (size_t)sB;
  float*  Cf = (float*) Cout + (size_t)blockIdx.z * (size_t)sC;
  __bf16* Ch = (__bf16*)Cout + (size_t)blockIdx.z * (size_t)sC;

  const int m0 = (blockIdx.x*4*MT + wave*MT)*16;

  bf16x8 Af[MT][KT];
#pragma unroll
  for (int mt=0; mt<MT; ++mt)
#pragma unroll
    for (int kt=0; kt<KT; ++kt)
      Af[mt][kt] = *(const bf16x8*)(Ab + (size_t)(m0 + mt*16 + fn)*K + kt*32 + fq*8);

  for (int n0 = blockIdx.y*16; n0 < Nn; n0 += 16*gridDim.y){
    const int gn = n0 + fn;
    const int gnc = (gn < Nn) ? gn : 0;
    f32x4 acc0[MT], acc1[MT];
#pragma unroll
    for (int mt=0; mt<MT; ++mt){
      acc0[mt] = (f32x4){0.f,0.f,0.f,0.f};
      acc1[mt] = (f32x4){0.f,0.f,0.f,0.f};
    }
#pragma unroll
    for (int kt=0; kt<KT; ++kt){
      bf16x8 Bf = *(const bf16x8*)(Bb + (size_t)gnc*K + kt*32 + fq*8);
      if (gn >= Nn) Bf = bzero8();
#pragma unroll
      for (int mt=0; mt<MT; ++mt){
        if (kt & 1) acc1[mt] = __builtin_amdgcn_mfma_f32_16x16x32_bf16(Af[mt][kt], Bf, acc1[mt], 0, 0, 0);
        else        acc0[mt] = __builtin_amdgcn_mfma_f32_16x16x32_bf16(Af[mt][kt], Bf, acc0[mt], 0, 0, 0);
      }
    }
    float bv = (bias && gn < Nn) ? bias[gn] : 0.f;
#pragma unroll
    for (int mt=0; mt<MT; ++mt){
#pragma unroll
      for (int r=0; r<4; ++r){
        int gm = m0 + mt*16 + fq*4 + r;
        float v = acc0[mt][r] + acc1[mt][r] + bv;
        if (ACT==1) v = selu_f(v);
        else if (ACT==2) v = fmaxf(v, 0.f);
        if (gn < Nn){
          if (OBF) Ch[(size_t)gm*ldc + gn] = (__bf16)v;
          else     Cf[(size_t)gm*ldc + gn] = v;
        } else if (gn < Npad){
          if (OBF) Ch[(size_t)gm*ldc + gn] = (__bf16)0.f;
          else     Cf[(size_t)gm*ldc + gn] = 0.f;
        }
      }
    }
  }
}

// ---------------- bf16 per-batch transpose [64][128][608] -> [64][608][128] ----------------
__global__ __launch_bounds__(256) void tr_k(
    const __bf16* __restrict__ in, __bf16* __restrict__ out)
{
  const int b = blockIdx.z, m0 = blockIdx.y*64, d0 = blockIdx.x*64;
  const int tid = threadIdx.x;
  __shared__ __align__(16) __bf16 T[64][72];
  const __bf16* ib = in + (size_t)b*NN_*DMP;
  __bf16* ob = out + (size_t)b*DMP*NN_;
#pragma unroll
  for (int r=0;r<2;++r){
    int idx = tid + 256*r;
    int mi = idx>>3, ch = idx&7;
    int d = d0 + ch*8;
    bf16x8 v = bzero8();
    if (d < DMP) v = *(const bf16x8*)(ib + (size_t)(m0+mi)*DMP + d);
    *(bf16x8*)&T[mi][ch*8] = v;
  }
  __syncthreads();
#pragma unroll
  for (int r=0;r<2;++r){
    int idx = tid + 256*r;
    int di = idx>>3, mch = idx&7;
    int d = d0 + di;
    if (d >= DMP) continue;
    bf16x8 v;
#pragma unroll
    for (int j=0;j<8;++j) v[j] = T[mch*8+j][di];
    *(bf16x8*)(ob + (size_t)d*NN_ + m0 + mch*8) = v;
  }
}

// ---------------- cooperative-cluster MFMA LSTM — R8 geometry, at protocol floor ----
__global__ __launch_bounds__(256, 1) void lstm_mfma_k(
    const __bf16* __restrict__ xg,
    const __bf16* __restrict__ wtb,
    __bf16* hist, int* flags,
    __bf16* __restrict__ ginb,
    const float* __restrict__ mask, float* __restrict__ aspect)
{
  const int blk = blockIdx.x;
  const int dir = blk / S_CL, sl = blk - dir*S_CL;
  const int tid = threadIdx.x, lane = tid & 63, wave = tid >> 6;
  const int p0 = sl * NSR;
  const __bf16* W = wtb + (size_t)dir * G4 * KPAD;
  __bf16* hb = hist + (size_t)dir * DSTR;

  const int fn = lane & 15, fq = lane >> 4, fk = fq*8;
  const int b  = wave*16 + fn;

  __shared__ volatile int done_s;
  __shared__ float mskL[NN_*BB];        // [n][b] transposed, 32 KB
  if (tid == 0) done_s = 0;
  for (int i = tid; i < BB*NN_; i += 256){
    int bb = i >> 7, nn = i & 127;
    mskL[nn*BB + bb] = mask[i];
  }

  bf16x8 Wf[3][10];
#pragma unroll
  for (int nt = 0; nt < 3; ++nt)
#pragma unroll
    for (int kt = 0; kt < 10; ++kt)
      Wf[nt][kt] = *(const bf16x8*)(W + (size_t)(p0 + nt*16 + fn)*KPAD + kt*32 + fk);

  float cst[3] = {0.f,0.f,0.f};
  float asp[3] = {0.f,0.f,0.f};
  float wnacc  = 0.f;
  const __bf16* xb = xg + (size_t)b*NN_*XGW + dir*G4 + p0 + fq*4;
  const int u0 = sl*NSU + fq;                 // + nt*4 -> unit in [0,300)
  __syncthreads();

  for (int s = 0; s < NN_; ++s){
    const int n_t = dir ? (NN_-1-s) : s;
    const __bf16* hbr = hb + (size_t)s*HSLOT + (size_t)b*KPAD;
    __bf16*       hbw = hb + (size_t)(s+1)*HSLOT + (size_t)b*KPAD;

    unsigned long long xv[3];
#pragma unroll
    for (int nt = 0; nt < 3; ++nt)
      xv[nt] = *(const unsigned long long*)(xb + (size_t)n_t*XGW + nt*16);
    const float mval = mskL[n_t*BB + b];

    bf16x8 Hf[10];
#pragma unroll
    for (int kt = 0; kt < 10; ++kt){
      const unsigned long long* hp = (const unsigned long long*)(hbr + kt*32 + fk);
      union { unsigned long long u[2]; bf16x8 v; } cv;
      cv.u[0] = __hip_atomic_load(hp,   __ATOMIC_RELAXED, COMM_SCOPE);
      cv.u[1] = __hip_atomic_load(hp+1, __ATOMIC_RELAXED, COMM_SCOPE);
      Hf[kt] = cv.v;
    }

    f32x4 acc[3] = { {0.f,0.f,0.f,0.f},{0.f,0.f,0.f,0.f},{0.f,0.f,0.f,0.f} };
#pragma unroll
    for (int kt = 0; kt < 10; ++kt)
#pragma unroll
      for (int nt = 0; nt < 3; ++nt)
        acc[nt] = __builtin_amdgcn_mfma_f32_16x16x32_bf16(Wf[nt][kt], Hf[kt], acc[nt], 0, 0, 0);

    __bf16 hsv[3];
#pragma unroll
    for (int nt = 0; nt < 3; ++nt){
      union { unsigned long long u; __bf16 g[4]; } xu; xu.u = xv[nt];
      float ig = sigm  (acc[nt][0] + (float)xu.g[0]);
      float fg = sigm  (acc[nt][1] + (float)xu.g[1]);
      float gg = tanh_f(acc[nt][2] + (float)xu.g[2]);
      float og = sigm  (acc[nt][3] + (float)xu.g[3]);
      float c = fg*cst[nt] + ig*gg; cst[nt] = c;
      float hval = og * tanh_f(c);
      asp[nt] += hval * mval;
      union { unsigned short us; __bf16 h; } pk; pk.h = (__bf16)hval;
      hsv[nt] = pk.h;
      // hist store MUST precede the flag -> stays in the pre-barrier drain.
      __hip_atomic_store((unsigned short*)(hbw + u0 + nt*4), pk.us,
                         __ATOMIC_RELAXED, COMM_SCOPE);
    }
    wnacc += mval;

    __syncthreads();   // drains hist stores (vmcnt0) before flag release
    if (tid == 0)
      __hip_atomic_store(&flags[(dir*S_CL + sl)*32], s+1,
                         __ATOMIC_RELAXED, COMM_SCOPE);
    // Deferred ginb stores: drain overlaps poll/next-step latency.
#pragma unroll
    for (int nt = 0; nt < 3; ++nt)
      ginb[(size_t)(b*NN_ + n_t)*DMP + dir*RHID + u0 + nt*4] = hsv[nt];
    if (wave < 2){
      if (wave == 1) __builtin_amdgcn_s_sleep(2);   // phase-offset the second poller
      int* fp = &flags[(dir*S_CL + (lane < S_CL ? lane : 0))*32];
      bool ok = (lane >= S_CL);
      while (done_s < s+1){
        if (!ok) ok = (__hip_atomic_load(fp, __ATOMIC_RELAXED, COMM_SCOPE) >= s+1);
        if (__all((int)ok)){ done_s = s+1; break; }
      }
    }
    __syncthreads();
  }

  const float invwn = 1.f / wnacc;
#pragma unroll
  for (int nt = 0; nt < 3; ++nt)
    aspect[b*DM + dir*RHID + u0 + nt*4] = asp[nt]*invwn;
}

// ---------------- fused: aw = aspect@WdM + bdM ; asc = tanh(aw·k + bias_m) ----------------
__global__ __launch_bounds__(128) void ascf_k(
    const float* __restrict__ aspect, const float* __restrict__ WdM, const float* __restrict__ bdM,
    const __bf16* __restrict__ qkh, const float* __restrict__ bias_m, float* __restrict__ asc)
{
  int b = blockIdx.x, h = blockIdx.y, t = threadIdx.x;
  __shared__ __align__(16) float asp[DM];
  __shared__ __align__(16) float awl[DKH];
  for (int i = t; i < DM; i += 128) asp[i] = aspect[b*DM + i];
  __syncthreads();
  if (t < DKH){
    const float* wrow = WdM + (size_t)h*DM*DKH + t;
    float s0=0.f,s1=0.f,s2=0.f,s3=0.f;
    for (int D=0; D<DM; D+=4){
      s0 += asp[D+0]*wrow[(size_t)(D+0)*DKH];
      s1 += asp[D+1]*wrow[(size_t)(D+1)*DKH];
      s2 += asp[D+2]*wrow[(size_t)(D+2)*DKH];
      s3 += asp[D+3]*wrow[(size_t)(D+3)*DKH];
    }
    awl[t] = s0+s1+s2+s3 + bdM[h*DKH + t];
  }
  __syncthreads();
  const __bf16* kr = qkh + (size_t)(b*NN_ + t)*QKL + 768 + h*128;
  float s=0.f;
#pragma unroll
  for (int e=0;e<DKH;e+=2){
    bf16x2 kv = *(const bf16x2*)(kr + e);
    s += awl[e]*(float)kv[0] + awl[e+1]*(float)kv[1];
  }
  asc[(b*NH+h)*NN_ + t] = tanhf(s + bias_m[0]);
}

// ---------------- MFMA attention (split x2): scores + mask + short + softmax -> adj bf16 ----------------
__global__ __launch_bounds__(256) void attn2_k(
    const __bf16* __restrict__ qkh, const float* __restrict__ asc,
    const float* __restrict__ shortm, const int* __restrict__ tok,
    __bf16* __restrict__ adj)
{
  const int bx = blockIdx.x;
  const int bh = bx >> 1, half = bx & 1;
  const int b = bh / NH, h = bh - b*NH;
  const int tid = threadIdx.x, lane = tid & 63, wave = tid >> 6;
  const int fn = lane & 15, fq = lane >> 4;
  const __bf16* qb = qkh + (size_t)(b*NN_)*QKL + h*128;
  const __bf16* kb = qkh + (size_t)(b*NN_)*QKL + 768 + h*128;

  const int m0 = half*64 + wave*16;
  bf16x8 Af[4];
#pragma unroll
  for (int kt=0;kt<4;++kt)
    Af[kt] = *(const bf16x8*)(qb + (size_t)(m0+fn)*QKL + kt*32 + fq*8);

  f32x4 acc[8];
#pragma unroll
  for (int j=0;j<8;++j) acc[j] = (f32x4){0.f,0.f,0.f,0.f};

#pragma unroll
  for (int j=0;j<8;++j){
    bf16x8 Bf[4];
#pragma unroll
    for (int kt=0;kt<4;++kt)
      Bf[kt] = *(const bf16x8*)(kb + (size_t)(j*16+fn)*QKL + kt*32 + fq*8);
#pragma unroll
    for (int kt=0;kt<4;++kt)
      acc[j] = __builtin_amdgcn_mfma_f32_16x16x32_bf16(Af[kt], Bf[kt], acc[j], 0,0,0);
  }

  float ascv[8]; int msk[8];
#pragma unroll
  for (int j=0;j<8;++j){
    int c = j*16 + fn;
    ascv[j] = asc[(b*NH+h)*NN_ + c];
    msk [j] = tok[b*NN_ + c];
  }

#pragma unroll
  for (int r=0;r<4;++r){
    int m = m0 + fq*4 + r;
    float sv[8];
#pragma unroll
    for (int j=0;j<8;++j){
      int c = j*16 + fn;
      float s = acc[j][r]*0.1f + ascv[j];
      if (msk[j]==0) s = -1e9f;
      s += shortm[((size_t)(b*NN_+m))*NN_ + c];
      sv[j]=s;
    }
    float mx = sv[0];
#pragma unroll
    for (int j=1;j<8;++j) mx = fmaxf(mx, sv[j]);
#pragma unroll
    for (int o=1;o<16;o<<=1) mx = fmaxf(mx, __shfl_xor(mx, o, 64));
    float sum = 0.f, ev[8];
#pragma unroll
    for (int j=0;j<8;++j){ ev[j]=__expf(sv[j]-mx); sum+=ev[j]; }
#pragma unroll
    for (int o=1;o<16;o<<=1) sum += __shfl_xor(sum, o, 64);
    float inv = 1.f/sum;
#pragma unroll
    for (int j=0;j<8;++j)
      adj[(((size_t)(b*NH+h))*NN_ + m)*NN_ + j*16 + fn] = (__bf16)(ev[j]*inv);
  }
}

// ---------------- adjsum (bf16 in) -> bf16 adjs (/H) + fp32 whs ----------------
__global__ __launch_bounds__(256) void adjsum_k(
    const __bf16* __restrict__ adj, const float* __restrict__ swx,
    __bf16* __restrict__ adjs, float* __restrict__ whs)
{
  int idx = blockIdx.x*256 + threadIdx.x;
  int b = idx >> 14, rem = idx & 16383;
  float s=0.f, w=0.f;
  for (int h=0;h<NH;++h){
    float v = (float)adj[(((size_t)b*NH+h)<<14) + rem];
    s += v; w += v*swx[h];
  }
  adjs[idx] = (__bf16)(s*(1.f/NH));
  whs [idx] = w*(1.f/NH);
}

// ---------------- adjs2[b,i,j] = whs + (sg1[b,j]+sg2[b,i]+sbx)/H -> bf16 ----------------
__global__ __launch_bounds__(256) void adjsum2_k(
    const float* __restrict__ whs, const float* __restrict__ sgi,
    const float* __restrict__ sbx, __bf16* __restrict__ adjs)
{
  int idx = blockIdx.x*256 + threadIdx.x;
  int b = idx >> 14, rem = idx & 16383;
  int i = rem >> 7, j = rem & 127;
  adjs[idx] = (__bf16)(whs[idx] + (sgi[(b*NN_+j)*2] + sgi[(b*NN_+i)*2+1] + sbx[0])*(1.f/NH));
}

// ---------------- pooled mean + logits (bf16 hn) ----------------
__global__ __launch_bounds__(320) void pooled_k(
    const __bf16* __restrict__ hn, const float* __restrict__ mask,
    const float* __restrict__ Wc, const float* __restrict__ bc, float* __restrict__ out)
{
  int b=blockIdx.x, t=threadIdx.x;
  __shared__ float msk[NN_];
  __shared__ float pl[RHID];
  __shared__ float wn;
  if (t<NN_) msk[t]=mask[b*NN_+t];
  __syncthreads();
  if (t==0){ float s=0.f; for (int n=0;n<NN_;++n) s+=msk[n]; wn=s; }
  __syncthreads();
  if (t<RHID){
    float s=0.f;
    for (int n=0;n<NN_;++n) s += (float)hn[((size_t)(b*NN_+n))*RHID+t]*msk[n];
    pl[t]=s/wn;
  }
  __syncthreads();
  if (t<3){
    float s=bc[t];
    for (int d=0;d<RHID;++d) s += pl[d]*Wc[t*RHID+d];
    out[b*3+t]=s;
  }
}

extern "C" void kernel_launch(void* const* d_in, const int* in_sizes, int n_in,
                              void* d_out, int out_size, void* d_ws, size_t ws_size,
                              hipStream_t stream)
{
  (void)in_sizes; (void)n_in; (void)out_size; (void)ws_size;
  const int*   tok      = (const int*)  d_in[0];
  const int*   pos_ids  = (const int*)  d_in[2];
  const int*   post_ids = (const int*)  d_in[5];
  const float* mask     = (const float*)d_in[6];
  const float* shortm   = (const float*)d_in[8];
  const float* emb_w    = (const float*)d_in[9];
  const float* pos_w    = (const float*)d_in[10];
  const float* post_w   = (const float*)d_in[11];
  const float* Wih_f    = (const float*)d_in[12];
  const float* Whh_f    = (const float*)d_in[13];
  const float* b_f      = (const float*)d_in[14];
  const float* Wih_b    = (const float*)d_in[15];
  const float* Whh_b    = (const float*)d_in[16];
  const float* b_b      = (const float*)d_in[17];
  const float* Wq       = (const float*)d_in[18];
  const float* bq       = (const float*)d_in[19];
  const float* Wk       = (const float*)d_in[20];
  const float* bk       = (const float*)d_in[21];
  const float* Wd       = (const float*)d_in[22];
  const float* bd       = (const float*)d_in[23];
  const float* weight_m = (const float*)d_in[24];
  const float* bias_m   = (const float*)d_in[25];
  const float* Ww       = (const float*)d_in[26];
  const float* bw       = (const float*)d_in[27];
  const float* Wx       = (const float*)d_in[28];
  const float* bx       = (const float*)d_in[29];
  const float* Wxx      = (const float*)d_in[30];
  const float* bxx      = (const float*)d_in[31];
  const float* Wc       = (const float*)d_in[32];
  const float* bc       = (const float*)d_in[33];

  float* ws  = (float*)d_ws;
  float* out = (float*)d_out;

  __bf16* ginb  = (__bf16*)(ws + OFF_GINB);
  float* aspect = ws + OFF_ASPECT;
  float* ascb   = ws + OFF_ASCB;
  float* w1sum  = ws + OFF_W1SUM;
  float* w2sum  = ws + OFF_W2SUM;
  float* swx    = ws + OFF_SWX;
  float* sbx    = ws + OFF_SBX;
  float* sgi    = ws + OFF_SGI;
  float* whs    = ws + OFF_WHS;
  __bf16* wqkp  = (__bf16*)(ws + OFF_WQKP);
  float* bqk    = ws + OFF_BQK;
  __bf16* wwp   = (__bf16*)(ws + OFF_WWP);
  __bf16* wxxp  = (__bf16*)(ws + OFF_WXXP);
  __bf16* wihp  = (__bf16*)(ws + OFF_WIHP);
  float* bp     = ws + OFF_BP;
  __bf16* wtb   = (__bf16*)(ws + OFF_WTB);
  __bf16* embs  = (__bf16*)(ws + OFF_EMBS);
  __bf16* xg    = (__bf16*)(ws + OFF_XG);
  __bf16* hist  = (__bf16*)(ws + OFF_HIST);
  int*   flags  = (int*)(ws + OFF_FLAGS);
  __bf16* qkh   = (__bf16*)(ws + OFF_QKH);
  __bf16* adjb  = (__bf16*)(ws + OFF_ADJ);
  __bf16* adjs  = (__bf16*)(ws + OFF_ADJS);
  __bf16* gint  = (__bf16*)(ws + OFF_GINT);
  __bf16* w12   = (__bf16*)(ws + OFF_W12);
  float* wdm    = ws + OFF_WDM;
  float* bdm    = ws + OFF_BDM;
  __bf16* axb   = (__bf16*)(ws + OFF_AXB);
  __bf16* g1b   = (__bf16*)(ws + OFF_G1B);
  __bf16* g1t   = (__bf16*)(ws + OFF_G1T);
  __bf16* ax2b  = (__bf16*)(ws + OFF_AX2B);
  __bf16* g2b   = (__bf16*)(ws + OFF_G2B);
  __bf16* hnb   = (__bf16*)(ws + OFF_HNB);

  // 1. embeddings, constants, fused packing/init (also zeroes ginb pad cols)
  embed_k<<<dim3(BB*NN_),384,0,stream>>>(tok,pos_ids,post_ids,emb_w,pos_w,post_w,embs);
  consts_k<<<1,640,0,stream>>>(Wx,bx,w1sum,w2sum,swx,sbx,w12);
  wdm_k<<<dim3(DM,NH),128,0,stream>>>(Wd,bd,weight_m,wdm,bdm);
  pack_k<<<dim3((PK6+255)/256),256,0,stream>>>(Wih_f,b_f,Wih_b,b_b,Wq,bq,Wk,bk,Ww,Wxx,
                                               Whh_f,Whh_b,wihp,bp,wqkp,bqk,wwp,wxxp,wtb,ws);
  // 2. merged LSTM input projection (both dirs), bf16 out [8192][2400] — MT=2
  wgemm_k<12,0,1,2><<<dim3(64,8,1),256,0,stream>>>(embs,wihp,bp,xg, XGW,XGW,XGW, 0,0,0);
  // 3. recurrence — R8 geometry (at protocol floor) + fast tanh.
  lstm_mfma_k<<<dim3(2*S_CL),256,0,stream>>>(xg,wtb,hist,flags,ginb,mask,aspect);
  // 4. fused Q||K projection (bf16 head-padded) — MT=2
  wgemm_k<19,0,1,2><<<dim3(64,12,1),256,0,stream>>>(ginb,wqkp,bqk,qkh, QKL,QKL,QKL, 0,0,0);
  ascf_k<<<dim3(BB,NH),128,0,stream>>>(aspect,wdm,bdm,qkh,bias_m,ascb);
  // 5. MFMA scores + softmax -> adj bf16
  attn2_k<<<dim3(BB*NH*2),256,0,stream>>>(qkh,ascb,shortm,tok,adjb);
  // 6. GCN layer 1 (bf16 MFMA) — MT=2 GEMMs
  adjsum_k<<<4096,256,0,stream>>>(adjb,swx,adjs,whs);
  tr_k<<<dim3(10,2,BB),256,0,stream>>>(ginb,gint);
  wgemm_k<4,0,1,2><<<dim3(1,4,BB),256,0,stream>>>(adjs,gint,nullptr,axb, DM,DMP,DMP, 16384,(long long)DMP*NN_,(long long)NN_*DMP);
  wgemm_k<19,1,1,2><<<dim3(64,8,1),256,0,stream>>>(axb,wwp,bw,g1b, DM,DMP,DMP, 0,0,0);
  // 7. layer-2 adjacency collapsed (sg via coalesced MFMA GEMV, N=2) — MT=2
  wgemm_k<19,0,0,2><<<dim3(64,1,1),256,0,stream>>>(g1b,w12,nullptr,sgi, 2,2,2, 0,0,0);
  adjsum2_k<<<4096,256,0,stream>>>(whs,sgi,sbx,adjs);
  // 8. GCN layer 2 — MT=2 GEMMs
  tr_k<<<dim3(10,2,BB),256,0,stream>>>(g1b,g1t);
  wgemm_k<4,0,1,2><<<dim3(1,4,BB),256,0,stream>>>(adjs,g1t,nullptr,ax2b, DM,DMP,DMP, 16384,(long long)DMP*NN_,(long long)NN_*DMP);
  wgemm_k<19,1,1,2><<<dim3(64,8,1),256,0,stream>>>(ax2b,wwp,bw,g2b, DM,DMP,DMP, 0,0,0);
  // 9. head (bf16 hnode out) — MT=2
  wgemm_k<19,2,1,2><<<dim3(64,4,1),256,0,stream>>>(g2b,wxxp,bxx,hnb, RHID,RHID,RHID, 0,0,0);
  pooled_k<<<BB,320,0,stream>>>(hnb,mask,Wc,bc,out);
}